// Round 14
// baseline (378.037 us; speedup 1.0000x reference)
//
#include <hip/hip_runtime.h>
#include <hip/hip_bf16.h>

#define BB 8
#define CC 128
#define NN 4096
#define HH 4
#define FF 128
#define KK 16
#define HF 512      // H*F
#define CAPH 128    // survivor capacity per query per half (stride 256 total)
#define WBUF 1536   // per-wave compaction buffer entries (20 sigma)

typedef __attribute__((ext_vector_type(8))) short short8v;
typedef __attribute__((ext_vector_type(8))) unsigned short ushort8v;
typedef __attribute__((ext_vector_type(4))) float f32x4;

__device__ __forceinline__ float bf2f(unsigned int u) {
  return __uint_as_float(u << 16);
}

__device__ __forceinline__ unsigned short f2bf(float f) {
  unsigned int u = __float_as_uint(f);
  unsigned int lsb = (u >> 16) & 1u;
  u += 0x7fffu + lsb;                 // RTNE
  return (unsigned short)(u >> 16);
}

__device__ __forceinline__ unsigned int umin2(unsigned int a, unsigned int b) {
  return a < b ? a : b;
}
__device__ __forceinline__ unsigned int umin3(unsigned int a, unsigned int b, unsigned int c) {
  return umin2(umin2(a, b), c);
}

// async global->LDS, 16B per lane; lds base must be wave-uniform
__device__ __forceinline__ void gload16(const void* gsrc, void* ldst) {
  __builtin_amdgcn_global_load_lds(
      (const __attribute__((address_space(1))) unsigned int*)gsrc,
      (__attribute__((address_space(3))) unsigned int*)ldst, 16, 0, 0);
}

// ---------------------------------------------------------------------------
// x[b][c][n] -> xt[b][n][c] (f32), xhi[b][n][c] (bf16), hsq[b][n] = 0.5*|x|^2
__launch_bounds__(256)
__global__ void k_split(const float* __restrict__ x,
                        float* __restrict__ xt,
                        unsigned short* __restrict__ xhi,
                        float* __restrict__ hsq) {
  __shared__ float Ls[CC][65];
  int b = blockIdx.x >> 6, nb = blockIdx.x & 63;
  int n0 = nb * 64;
  int tid = threadIdx.x;
  const float* xb = x + (size_t)b * CC * NN;

  for (int i = tid; i < CC * 64; i += 256) {
    int c = i >> 6, nl = i & 63;
    Ls[c][nl] = xb[(size_t)c * NN + n0 + nl];
  }
  __syncthreads();

  int n = tid >> 2, part = tid & 3;     // 64 n x 4 parts (32 c each)
  int node = b * NN + n0 + n;
  float sum = 0.f;
#pragma unroll
  for (int g = 0; g < 4; ++g) {
    float v[8];
    ushort8v ph;
#pragma unroll
    for (int j = 0; j < 8; ++j) {
      int c = part * 32 + g * 8 + j;
      v[j] = Ls[c][n];
      ph[j] = f2bf(v[j]);
      sum += v[j] * v[j];
    }
    float4 f0 = {v[0], v[1], v[2], v[3]};
    float4 f1 = {v[4], v[5], v[6], v[7]};
    *(float4*)&xt[(size_t)node * CC + part * 32 + g * 8] = f0;
    *(float4*)&xt[(size_t)node * CC + part * 32 + g * 8 + 4] = f1;
    *(ushort8v*)&xhi[(size_t)node * CC + part * 32 + g * 8] = ph;
  }
  sum += __shfl_xor(sum, 1, 64);
  sum += __shfl_xor(sum, 2, 64);
  if (part == 0) hsq[node] = 0.5f * sum;
}

// ---------------------------------------------------------------------------
// Pack W[c][hf] f32 -> Whi/Wlo[hf][c] bf16
__global__ void k_wpack(const float* __restrict__ W,
                        unsigned short* __restrict__ Whi,
                        unsigned short* __restrict__ Wlo) {
  int i = blockIdx.x * 256 + threadIdx.x;   // over 512*128
  int hf = i >> 7, c = i & 127;
  float v = W[(size_t)c * HF + hf];
  unsigned short hb = f2bf(v);
  Whi[i] = hb;
  Wlo[i] = f2bf(v - bf2f(hb));
}

// ---------------------------------------------------------------------------
// tau scan, split into 2 half-subset blocks per query group: each block scans
// 512 candidates (32 tiles) and writes per-query top-16 KEY VALUES to keys16.
// LDS-staged (double-buffered gload16, XOR swizzle); mv padded [65] (2-way
// bank = free). XCD-pinned: batch = blockIdx & 7.
__launch_bounds__(256)
__global__ void k_tauscan(const unsigned short* __restrict__ xhi,
                          const float* __restrict__ hsq,
                          unsigned int* __restrict__ keys16) {
  __shared__ short8v AS[2][256];           // 8 KB staging (16 nodes x 16 granules)
  __shared__ unsigned int mv[4][16][65];   // 16.6 KB (padded: conflict-free dump)
  int bx = blockIdx.x;
  int b = bx & 7, rest = bx >> 3;          // XCD-pinned; rest 0..127
  int qg = rest >> 1, sh = rest & 1;       // scan-half
  int w = threadIdx.x >> 6, lane = threadIdx.x & 63;
  int qcol = lane & 15, kg = lane >> 4;
  int base = b * NN;
  int q = base + qg * 64 + w * 16 + qcol;
  int t0 = sh * 32;

  const short8v* XH = (const short8v*)xhi;   // granules: node*16 + ks*4 + kg
  short8v bh0 = XH[(size_t)q * 16 + kg];
  short8v bh1 = XH[(size_t)q * 16 + 4 + kg];
  short8v bh2 = XH[(size_t)q * 16 + 8 + kg];
  short8v bh3 = XH[(size_t)q * 16 + 12 + kg];

  int snode = w * 4 + (lane >> 4);
  int sgran = (lane & 15) ^ (snode & 15);

  gload16(xhi + ((size_t)(base + t0 * 16 + snode)) * 128 + sgran * 8, &AS[0][w * 64]);
  __syncthreads();

  unsigned int bd[16];
  unsigned int worst = 0;
  int cur = 0;

#pragma unroll 1
  for (int lt = 0; lt < 32; ++lt) {
    if (lt + 1 < 32)
      gload16(xhi + ((size_t)(base + (t0 + lt + 1) * 16 + snode)) * 128 + sgran * 8,
              &AS[cur ^ 1][w * 64]);
    short8v ah0 = AS[cur][qcol * 16 + ((0 + kg) ^ qcol)];
    short8v ah1 = AS[cur][qcol * 16 + ((4 + kg) ^ qcol)];
    short8v ah2 = AS[cur][qcol * 16 + ((8 + kg) ^ qcol)];
    short8v ah3 = AS[cur][qcol * 16 + ((12 + kg) ^ qcol)];
    f32x4 acc = {0.f, 0.f, 0.f, 0.f};
    acc = __builtin_amdgcn_mfma_f32_16x16x32_bf16(ah0, bh0, acc, 0, 0, 0);
    acc = __builtin_amdgcn_mfma_f32_16x16x32_bf16(ah1, bh1, acc, 0, 0, 0);
    acc = __builtin_amdgcn_mfma_f32_16x16x32_bf16(ah2, bh2, acc, 0, 0, 0);
    acc = __builtin_amdgcn_mfma_f32_16x16x32_bf16(ah3, bh3, acc, 0, 0, 0);
    float4 hs = *(const float4*)&hsq[base + (t0 + lt) * 16 + kg * 4];
    float hsa[4] = {hs.x, hs.y, hs.z, hs.w};

    if (lt < 4) {
#pragma unroll
      for (int r = 0; r < 4; ++r) {
        float tv = acc[r] - hsa[r] + 512.0f;
        bd[lt * 4 + r] = (__float_as_uint(tv) & ~1023u) | (1023u - (unsigned)(lt * 4 + r));
      }
      if (lt == 3) {
        unsigned int m0 = umin3(bd[0], bd[1], bd[2]);
        m0 = umin3(m0, bd[3], bd[4]);
        m0 = umin3(m0, bd[5], bd[6]);
        m0 = umin2(m0, bd[7]);
        unsigned int m1 = umin3(bd[8], bd[9], bd[10]);
        m1 = umin3(m1, bd[11], bd[12]);
        m1 = umin3(m1, bd[13], bd[14]);
        m1 = umin2(m1, bd[15]);
        worst = umin2(m0, m1);
      }
    } else {
#pragma unroll
      for (int r = 0; r < 4; ++r) {
        float tv = acc[r] - hsa[r] + 512.0f;
        unsigned int key = (__float_as_uint(tv) & ~1023u) | (1023u - (unsigned)(lt * 4 + r));
        if (key > worst) {
#pragma unroll
          for (int i = 0; i < 16; ++i) bd[i] = (bd[i] == worst) ? key : bd[i];
          unsigned int n0_ = umin3(bd[0], bd[1], bd[2]);
          n0_ = umin3(n0_, bd[3], bd[4]);
          n0_ = umin3(n0_, bd[5], bd[6]);
          n0_ = umin2(n0_, bd[7]);
          unsigned int n1_ = umin3(bd[8], bd[9], bd[10]);
          n1_ = umin3(n1_, bd[11], bd[12]);
          n1_ = umin3(n1_, bd[13], bd[14]);
          n1_ = umin2(n1_, bd[15]);
          worst = umin2(n0_, n1_);
        }
      }
    }
    __syncthreads();
    cur ^= 1;
  }

#pragma unroll
  for (int i = 0; i < 16; ++i) mv[w][qcol][kg * 16 + i] = bd[i];
  __syncthreads();

  if (lane < 16) {
    unsigned int tb[16];
#pragma unroll
    for (int i = 0; i < 16; ++i) tb[i] = mv[w][lane][i];
    unsigned int w0 = umin3(tb[0], tb[1], tb[2]);
    w0 = umin3(w0, tb[3], tb[4]);
    w0 = umin3(w0, tb[5], tb[6]);
    w0 = umin2(w0, tb[7]);
    unsigned int w1 = umin3(tb[8], tb[9], tb[10]);
    w1 = umin3(w1, tb[11], tb[12]);
    w1 = umin3(w1, tb[13], tb[14]);
    w1 = umin2(w1, tb[15]);
    unsigned int wst = umin2(w0, w1);
    for (int j = 16; j < 64; ++j) {
      unsigned int v = mv[w][lane][j];
      if (v > wst) {
        bool done = false;
#pragma unroll
        for (int i = 0; i < 16; ++i) {
          bool m = (!done) && (tb[i] == wst);
          done = done || m;
          tb[i] = m ? v : tb[i];
        }
        unsigned int a0 = umin3(tb[0], tb[1], tb[2]);
        a0 = umin3(a0, tb[3], tb[4]);
        a0 = umin3(a0, tb[5], tb[6]);
        a0 = umin2(a0, tb[7]);
        unsigned int a1 = umin3(tb[8], tb[9], tb[10]);
        a1 = umin3(a1, tb[11], tb[12]);
        a1 = umin3(a1, tb[13], tb[14]);
        a1 = umin2(a1, tb[15]);
        wst = umin2(a0, a1);
      }
    }
    int qq = base + qg * 64 + w * 16 + lane;
    unsigned int* o = keys16 + ((size_t)qq * 2 + sh) * 16;
#pragma unroll
    for (int i = 0; i < 16; ++i) o[i] = tb[i];
  }
}

// ---------------------------------------------------------------------------
// Merge per-half top-16 keys -> 16th-largest of union (== 16th of full
// 1024-subset) -> thr[q] = floor16(key) - 0.5. One thread per query.
__launch_bounds__(256)
__global__ void k_taumerge(const unsigned int* __restrict__ keys16,
                           float* __restrict__ thr) {
  int q = blockIdx.x * 256 + threadIdx.x;
  const unsigned int* kp = keys16 + (size_t)q * 32;
  unsigned int tb[16];
#pragma unroll
  for (int i = 0; i < 16; ++i) tb[i] = kp[i];
  unsigned int w0 = umin3(tb[0], tb[1], tb[2]);
  w0 = umin3(w0, tb[3], tb[4]);
  w0 = umin3(w0, tb[5], tb[6]);
  w0 = umin2(w0, tb[7]);
  unsigned int w1 = umin3(tb[8], tb[9], tb[10]);
  w1 = umin3(w1, tb[11], tb[12]);
  w1 = umin3(w1, tb[13], tb[14]);
  w1 = umin2(w1, tb[15]);
  unsigned int wst = umin2(w0, w1);
#pragma unroll 1
  for (int j = 16; j < 32; ++j) {
    unsigned int v = kp[j];
    if (v > wst) {
      bool done = false;
#pragma unroll
      for (int i = 0; i < 16; ++i) {
        bool m = (!done) && (tb[i] == wst);
        done = done || m;
        tb[i] = m ? v : tb[i];
      }
      unsigned int a0 = umin3(tb[0], tb[1], tb[2]);
      a0 = umin3(a0, tb[3], tb[4]);
      a0 = umin3(a0, tb[5], tb[6]);
      a0 = umin2(a0, tb[7]);
      unsigned int a1 = umin3(tb[8], tb[9], tb[10]);
      a1 = umin3(a1, tb[11], tb[12]);
      a1 = umin3(a1, tb[13], tb[14]);
      a1 = umin2(a1, tb[15]);
      wst = umin2(a0, a1);
    }
  }
  thr[q] = __uint_as_float(wst & ~1023u) - 0.5f;
}

// ---------------------------------------------------------------------------
// Collect survivors (tv >= thr[q]): LDS-staged tiles + ballot-compaction into
// per-wave LDS list, then bucket into per-(query,half) global lists.
// XCD-pinned: batch = blockIdx & 7.
__launch_bounds__(256)
__global__ void k_collect2(const unsigned short* __restrict__ xhi,
                           const float* __restrict__ hsq,
                           const float* __restrict__ thr,
                           unsigned short* __restrict__ cand,
                           unsigned short* __restrict__ qcnt) {
  __shared__ short8v AS[2][256];          // 8 KB staging
  __shared__ unsigned int buf[4][WBUF];   // 24 KB
  __shared__ unsigned int qc[4][16];
  int bx = blockIdx.x;
  int b = bx & 7, rest = bx >> 3;         // XCD-pinned batch; rest 0..127
  int qg = rest >> 1, ht = rest & 1;
  int w = threadIdx.x >> 6, lane = threadIdx.x & 63;
  int qcol = lane & 15, kg = lane >> 4;
  int base = b * NN;
  int q = base + qg * 64 + w * 16 + qcol;

  const short8v* XH = (const short8v*)xhi;
  short8v bh0 = XH[(size_t)q * 16 + kg];
  short8v bh1 = XH[(size_t)q * 16 + 4 + kg];
  short8v bh2 = XH[(size_t)q * 16 + 8 + kg];
  short8v bh3 = XH[(size_t)q * 16 + 12 + kg];
  float myThr = thr[q];
  if (lane < 16) qc[w][lane] = 0;

  int snode = w * 4 + (lane >> 4);
  int sgran = (lane & 15) ^ (snode & 15);

  gload16(xhi + ((size_t)(base + (ht * 128) * 16 + snode)) * 128 + sgran * 8,
          &AS[0][w * 64]);
  __syncthreads();

  int wbase = 0;
  unsigned long long ltmask = (1ull << lane) - 1ull;
  int cur = 0;

#pragma unroll 1
  for (int lt = 0; lt < 128; ++lt) {
    int t = ht * 128 + lt;
    if (lt + 1 < 128)
      gload16(xhi + ((size_t)(base + (t + 1) * 16 + snode)) * 128 + sgran * 8,
              &AS[cur ^ 1][w * 64]);
    short8v ah0 = AS[cur][qcol * 16 + ((0 + kg) ^ qcol)];
    short8v ah1 = AS[cur][qcol * 16 + ((4 + kg) ^ qcol)];
    short8v ah2 = AS[cur][qcol * 16 + ((8 + kg) ^ qcol)];
    short8v ah3 = AS[cur][qcol * 16 + ((12 + kg) ^ qcol)];
    f32x4 acc = {0.f, 0.f, 0.f, 0.f};
    acc = __builtin_amdgcn_mfma_f32_16x16x32_bf16(ah0, bh0, acc, 0, 0, 0);
    acc = __builtin_amdgcn_mfma_f32_16x16x32_bf16(ah1, bh1, acc, 0, 0, 0);
    acc = __builtin_amdgcn_mfma_f32_16x16x32_bf16(ah2, bh2, acc, 0, 0, 0);
    acc = __builtin_amdgcn_mfma_f32_16x16x32_bf16(ah3, bh3, acc, 0, 0, 0);
    float4 hs = *(const float4*)&hsq[base + t * 16 + kg * 4];
    float hsa[4] = {hs.x, hs.y, hs.z, hs.w};
#pragma unroll
    for (int r = 0; r < 4; ++r) {
      float tv = acc[r] - hsa[r] + 512.0f;
      bool pass = tv >= myThr;
      unsigned long long mask = __ballot(pass);
      if (mask) {
        int pos = wbase + (int)__popcll(mask & ltmask);
        if (pass && pos < WBUF)
          buf[w][pos] = ((unsigned)qcol << 12) | (unsigned)(t * 16 + kg * 4 + r);
        wbase += (int)__popcll(mask);
      }
    }
    __syncthreads();
    cur ^= 1;
  }
  if (wbase > WBUF) wbase = WBUF;

  for (int i = lane; i < wbase; i += 64) {
    unsigned int e = buf[w][i];
    int ql = (int)(e >> 12);
    unsigned int slot = atomicAdd(&qc[w][ql], 1u);
    if (slot < CAPH)
      cand[(size_t)(base + qg * 64 + w * 16 + ql) * (2 * CAPH) + ht * CAPH + slot] =
          (unsigned short)(e & 0xfffu);
  }
  __syncthreads();

  if (lane < 16) {
    unsigned int c = qc[w][lane];
    if (c > CAPH) c = CAPH;
    qcnt[(size_t)(base + qg * 64 + w * 16 + lane) * 2 + ht] = (unsigned short)c;
  }
}

// ---------------------------------------------------------------------------
// Exact f32 rerank, 8-lane cooperative dot phase; selection via per-lane
// sorted-4 lists + val-only butterfly argmax + ballot/ffs winner broadcast.
__launch_bounds__(256)
__global__ void k_rerank(const float* __restrict__ xt, const float* __restrict__ hsq,
                         const unsigned short* __restrict__ cand,
                         const unsigned short* __restrict__ qcnt,
                         unsigned short* __restrict__ nbr) {
  __shared__ float pv[4][256];
  int w = threadIdx.x >> 6;
  int bid = blockIdx.x;
  int b = bid & 7, inner = bid >> 3;      // XCD-pinned batch; inner 0..1023
  int wq = (b << 12) + inner * 4 + w;
  int lane = threadIdx.x & 63;
  int base = b * NN;
  int n0 = qcnt[(size_t)wq * 2];
  int n1 = qcnt[(size_t)wq * 2 + 1];
  int nt = n0 + n1;                       // <= 256
  const float* qr = xt + (size_t)wq * CC;
  int cid = lane >> 3, part = lane & 7;

  float4 qv[4];
#pragma unroll
  for (int ph = 0; ph < 4; ++ph)
    qv[ph] = *(const float4*)&qr[ph * 32 + part * 4];

  int npass = (nt + 7) >> 3;
#pragma unroll 2
  for (int p = 0; p < npass; ++p) {
    int j = p * 8 + cid;
    bool valid = j < nt;
    int c = 0;
    if (valid)
      c = (j < n0) ? cand[(size_t)wq * (2 * CAPH) + j]
                   : cand[(size_t)wq * (2 * CAPH) + CAPH + (j - n0)];
    const float* cr = xt + (size_t)(base + c) * CC;
    float acc = 0.f;
#pragma unroll
    for (int ph = 0; ph < 4; ++ph) {
      float4 cv = *(const float4*)&cr[ph * 32 + part * 4];
      acc = fmaf(qv[ph].x, cv.x, acc);
      acc = fmaf(qv[ph].y, cv.y, acc);
      acc = fmaf(qv[ph].z, cv.z, acc);
      acc = fmaf(qv[ph].w, cv.w, acc);
    }
    acc += __shfl_xor(acc, 1, 64);
    acc += __shfl_xor(acc, 2, 64);
    acc += __shfl_xor(acc, 4, 64);
    if (part == 0)
      pv[w][p * 8 + cid] = valid ? (acc - hsq[base + c]) : -3.4e38f;
  }

  float v0, v1, v2, v3;
  int i0, i1, i2, i3;
  {
    float tv[4]; int ti[4];
#pragma unroll
    for (int s = 0; s < 4; ++s) {
      int j = lane + s * 64;
      if (j < nt) {
        tv[s] = pv[w][j];
        ti[s] = (j < n0) ? cand[(size_t)wq * (2 * CAPH) + j]
                         : cand[(size_t)wq * (2 * CAPH) + CAPH + (j - n0)];
      } else {
        tv[s] = -3.4e38f; ti[s] = 0x7fffffff;
      }
    }
    v0 = tv[0]; v1 = tv[1]; v2 = tv[2]; v3 = tv[3];
    i0 = ti[0]; i1 = ti[1]; i2 = ti[2]; i3 = ti[3];
  }
#define CE(va, ia, vb, ib)                                        \
  {                                                               \
    bool sw_ = (vb > va) || (vb == va && ib < ia);                \
    float tv_ = va; int ti_ = ia;                                 \
    va = sw_ ? vb : va; ia = sw_ ? ib : ia;                       \
    vb = sw_ ? tv_ : vb; ib = sw_ ? ti_ : ib;                     \
  }
  CE(v0, i0, v1, i1); CE(v2, i2, v3, i3);
  CE(v0, i0, v2, i2); CE(v1, i1, v3, i3);
  CE(v1, i1, v2, i2);
#undef CE

  unsigned short* o = nbr + (size_t)wq * KK;
  for (int s = 0; s < KK; ++s) {
    float bv = v0;
#pragma unroll
    for (int off = 1; off < 64; off <<= 1)
      bv = fmaxf(bv, __shfl_xor(bv, off, 64));
    unsigned long long own = __ballot(v0 == bv);
    int wi;
    bool owner;
    if (__popcll(own) > 1) {           // exact-tie path (wave-uniform, rare)
      int ci = (v0 == bv) ? i0 : 0x7fffffff;
#pragma unroll
      for (int off = 1; off < 64; off <<= 1) {
        int oc = __shfl_xor(ci, off, 64);
        ci = oc < ci ? oc : ci;
      }
      wi = ci;
      owner = (v0 == bv) && (i0 == ci);
    } else {
      int first = (int)__ffsll((unsigned long long)own) - 1;
      wi = __shfl(i0, first, 64);
      owner = (lane == first);
    }
    if (lane == 0) o[s] = (unsigned short)wi;
    if (owner) {
      v0 = v1; i0 = i1;
      v1 = v2; i1 = i2;
      v2 = v3; i2 = i3;
      v3 = -3.4e38f; i3 = 0x7fffffff;
    }
  }
}

// ---------------------------------------------------------------------------
// h = xt . W via 3-term split-bf16 MFMA (xhi*Whi + xhi*Wlo + xlo*Whi), bf16 out
__launch_bounds__(256)
__global__ void k_h2(const float* __restrict__ xt,
                     const unsigned short* __restrict__ Whi,
                     const unsigned short* __restrict__ Wlo,
                     unsigned short* __restrict__ hout) {
  int w = threadIdx.x >> 6, lane = threadIdx.x & 63;
  int r16 = lane & 15, kg = lane >> 4;
  int nd0 = blockIdx.x * 64 + w * 16;
  const float* arow = xt + (size_t)(nd0 + r16) * CC;
  short8v ahi[4], alo[4];
#pragma unroll
  for (int ks = 0; ks < 4; ++ks) {
    float4 f0 = *(const float4*)&arow[ks * 32 + kg * 8];
    float4 f1 = *(const float4*)&arow[ks * 32 + kg * 8 + 4];
    float fv[8] = {f0.x, f0.y, f0.z, f0.w, f1.x, f1.y, f1.z, f1.w};
    short8v hh_, ll_;
#pragma unroll
    for (int j = 0; j < 8; ++j) {
      unsigned short hb = f2bf(fv[j]);
      hh_[j] = (short)hb;
      ll_[j] = (short)f2bf(fv[j] - bf2f(hb));
    }
    ahi[ks] = hh_; alo[ks] = ll_;
  }
  const short8v* WH = (const short8v*)Whi;   // granule: hf*16 + ks*4 + kg
  const short8v* WL = (const short8v*)Wlo;
#pragma unroll 1
  for (int ct = 0; ct < 32; ++ct) {
    int hf = ct * 16 + r16;
    f32x4 acc = {0.f, 0.f, 0.f, 0.f};
#pragma unroll
    for (int ks = 0; ks < 4; ++ks) {
      short8v bh = WH[(size_t)hf * 16 + ks * 4 + kg];
      short8v bl = WL[(size_t)hf * 16 + ks * 4 + kg];
      acc = __builtin_amdgcn_mfma_f32_16x16x32_bf16(ahi[ks], bh, acc, 0, 0, 0);
      acc = __builtin_amdgcn_mfma_f32_16x16x32_bf16(ahi[ks], bl, acc, 0, 0, 0);
      acc = __builtin_amdgcn_mfma_f32_16x16x32_bf16(alo[ks], bh, acc, 0, 0, 0);
    }
#pragma unroll
    for (int r = 0; r < 4; ++r)
      hout[(size_t)(nd0 + kg * 4 + r) * HF + hf] = f2bf(acc[r]);
  }
}

// ---------------------------------------------------------------------------
// a_src/a_dst[b][n][h] = sum_f h[b][n][h][f] * att_{src,dst}[h][f]
__global__ void k_att(const unsigned short* __restrict__ h,
                      const float* __restrict__ att_src, const float* __restrict__ att_dst,
                      float* __restrict__ a_src, float* __restrict__ a_dst) {
  int gid = blockIdx.x * 256 + threadIdx.x;
  int wid = gid >> 6;            // node index b*N+n
  int lane = threadIdx.x & 63;
  uint4 v = ((const uint4*)(h + (size_t)wid * HF))[lane];
  float hv[8];
  hv[0] = bf2f(v.x & 0xffff); hv[1] = bf2f(v.x >> 16);
  hv[2] = bf2f(v.y & 0xffff); hv[3] = bf2f(v.y >> 16);
  hv[4] = bf2f(v.z & 0xffff); hv[5] = bf2f(v.z >> 16);
  hv[6] = bf2f(v.w & 0xffff); hv[7] = bf2f(v.w >> 16);
  int base = lane * 8;
  float s = 0.f, d = 0.f;
#pragma unroll
  for (int i = 0; i < 8; ++i) {
    s += hv[i] * att_src[base + i];
    d += hv[i] * att_dst[base + i];
  }
#pragma unroll
  for (int off = 1; off < 16; off <<= 1) {
    s += __shfl_xor(s, off, 64);
    d += __shfl_xor(d, off, 64);
  }
  if ((lane & 15) == 0) {
    int hh = lane >> 4;
    a_src[wid * HH + hh] = s;
    a_dst[wid * HH + hh] = d;
  }
}

// ---------------------------------------------------------------------------
// gather + softmax(k=16) + weighted sum + head-mean + bias + transpose store
// XCD-pinned: batch = blockIdx & 7 (h slab 4.2 MB/batch ~ L2-resident).
__launch_bounds__(256)
__global__ void k_out(const unsigned short* __restrict__ h,
                      const unsigned short* __restrict__ nbr,
                      const float* __restrict__ a_src, const float* __restrict__ a_dst,
                      const float* __restrict__ bias, float* __restrict__ out) {
  __shared__ float Ot[FF][17];
  int b = blockIdx.x & 7, nb = blockIdx.x >> 3;   // XCD-pinned batch; nb 0..255
  int w = threadIdx.x >> 6, lane = threadIdx.x & 63;
  int hh = lane >> 4, jj = lane & 15;

  for (int t = 0; t < 4; ++t) {
    int nl = w * 4 + t;
    int node = b * NN + nb * 16 + nl;
    int mj = nbr[node * KK + jj];

    float e = a_src[((size_t)b * NN + mj) * HH + hh] + a_dst[(size_t)node * HH + hh];
    e = e >= 0.f ? e : 0.2f * e;
    float m = e;
#pragma unroll
    for (int off = 1; off < 16; off <<= 1) m = fmaxf(m, __shfl_xor(m, off, 64));
    float p = expf(e - m);
    float sum = p;
#pragma unroll
    for (int off = 1; off < 16; off <<= 1) sum += __shfl_xor(sum, off, 64);
    float alpha = p / sum;

    float acc[8];
#pragma unroll
    for (int i = 0; i < 8; ++i) acc[i] = 0.f;

#pragma unroll
    for (int j = 0; j < 16; ++j) {
      float aj = __shfl(alpha, (hh << 4) | j, 64);
      int m2 = __shfl(mj, j, 64);
      uint4 v = ((const uint4*)(h + (size_t)(b * NN + m2) * HF))[lane];
      acc[0] += aj * bf2f(v.x & 0xffff); acc[1] += aj * bf2f(v.x >> 16);
      acc[2] += aj * bf2f(v.y & 0xffff); acc[3] += aj * bf2f(v.y >> 16);
      acc[4] += aj * bf2f(v.z & 0xffff); acc[5] += aj * bf2f(v.z >> 16);
      acc[6] += aj * bf2f(v.w & 0xffff); acc[7] += aj * bf2f(v.w >> 16);
    }

#pragma unroll
    for (int i = 0; i < 8; ++i) {
      acc[i] += __shfl_xor(acc[i], 16, 64);
      acc[i] += __shfl_xor(acc[i], 32, 64);
    }
    if (hh == 0) {
#pragma unroll
      for (int i = 0; i < 8; ++i) Ot[jj * 8 + i][nl] = acc[i] * 0.25f;
    }
  }
  __syncthreads();

#pragma unroll
  for (int it = 0; it < 8; ++it) {
    int idx = it * 256 + threadIdx.x;
    int f = idx >> 4, nl = idx & 15;
    out[((size_t)b * FF + f) * NN + nb * 16 + nl] = Ot[f][nl] + bias[f];
  }
}

// ---------------------------------------------------------------------------
extern "C" void kernel_launch(void* const* d_in, const int* in_sizes, int n_in,
                              void* d_out, int out_size, void* d_ws, size_t ws_size,
                              hipStream_t stream) {
  const float* x       = (const float*)d_in[0];
  const float* W       = (const float*)d_in[1];
  const float* att_src = (const float*)d_in[2];
  const float* att_dst = (const float*)d_in[3];
  const float* bias    = (const float*)d_in[4];

  char* ws = (char*)d_ws;
  // Lifetime-aliased layout; all sizes verified numerically (same as R8-R13,
  // plus keys16 aliased into the pre-collect2 cand region):
  //   [0        ,16777216): xt    f32 32768*128*4 = 16,777,216 — split..rerank,h2
  //   [16777216 ,25165824): xhi   bf16 32768*128*2 = 8,388,608 — split..collect2
  //   [25165824 ,30360128): keys16 u32 32768*32*4 = 4,194,304  — tauscan..taumerge
  //   [25165824 ,41943040): cand  u16 32768*256*2 = 16,777,216 — collect2..rerank
  //       (keys16 dead before collect2 writes cand — lifetime-disjoint)
  //   [16777216 ,50331648): h     bf16 32768*512*2 = 33,554,432 — k_h2 AFTER rerank
  //   [50331648 ,51380224): nbr   u16 32768*16*2 = 1,048,576   — rerank..out
  //   [51380224 ,51511296): qcnt  u16 32768*2*2 = 131,072      — collect2..rerank
  //   [51511296 ,51642368): thr   f32 32768*4 = 131,072        — taumerge..collect2
  //   [51642368 ,51773440): hsq   f32 32768*4 = 131,072        — split..rerank
  //   [51773440 ,52297728): a_src f32 524,288 (aliased early by Whi+Wlo 2*131,072)
  //   [52297728 ,52822016): a_dst f32 524,288
  // total 52,822,016 B (proven envelope)
  float* xt            = (float*)ws;
  unsigned short* xhi  = (unsigned short*)(ws + 16777216);
  unsigned int* keys16 = (unsigned int*)(ws + 25165824);
  unsigned short* cand = (unsigned short*)(ws + 25165824);
  unsigned short* h    = (unsigned short*)(ws + 16777216);
  unsigned short* nbr  = (unsigned short*)(ws + 50331648);
  unsigned short* qcnt = (unsigned short*)(ws + 51380224);
  float* thr   = (float*)(ws + 51511296);
  float* hsq   = (float*)(ws + 51642368);
  float* a_src = (float*)(ws + 51773440);
  unsigned short* Whi  = (unsigned short*)(ws + 51773440);
  unsigned short* Wlo  = (unsigned short*)(ws + 51773440 + 131072);
  float* a_dst = (float*)(ws + 52297728);

  float* out = (float*)d_out;

  k_split   <<<BB * (NN / 64), 256, 0, stream>>>(x, xt, xhi, hsq);
  k_wpack   <<<HF * CC / 256, 256, 0, stream>>>(W, Whi, Wlo);
  k_tauscan <<<BB * 64 * 2, 256, 0, stream>>>(xhi, hsq, keys16);
  k_taumerge<<<BB * NN / 256, 256, 0, stream>>>(keys16, thr);
  k_collect2<<<BB * 64 * 2, 256, 0, stream>>>(xhi, hsq, thr, cand, qcnt);
  k_rerank  <<<BB * NN / 4, 256, 0, stream>>>(xt, hsq, cand, qcnt, nbr);
  k_h2      <<<BB * NN / 64, 256, 0, stream>>>(xt, Whi, Wlo, h);
  k_att     <<<BB * NN / 4, 256, 0, stream>>>(h, att_src, att_dst, a_src, a_dst);
  k_out     <<<BB * (NN / 16), 256, 0, stream>>>(h, nbr, a_src, a_dst, bias, out);
}

// Round 15
// 338.105 us; speedup vs baseline: 1.1181x; 1.1181x over previous
//
#include <hip/hip_runtime.h>
#include <hip/hip_bf16.h>

#define BB 8
#define CC 128
#define NN 4096
#define HH 4
#define FF 128
#define KK 16
#define HF 512      // H*F
#define CAPH 128    // survivor capacity per query per half (stride 256 total)
#define LCAP 32     // per-lane private survivor list cap (mu 8.75 + 7.9 sigma)

typedef __attribute__((ext_vector_type(8))) short short8v;
typedef __attribute__((ext_vector_type(8))) unsigned short ushort8v;
typedef __attribute__((ext_vector_type(4))) float f32x4;

__device__ __forceinline__ float bf2f(unsigned int u) {
  return __uint_as_float(u << 16);
}

__device__ __forceinline__ unsigned short f2bf(float f) {
  unsigned int u = __float_as_uint(f);
  unsigned int lsb = (u >> 16) & 1u;
  u += 0x7fffu + lsb;                 // RTNE
  return (unsigned short)(u >> 16);
}

__device__ __forceinline__ unsigned int umin2(unsigned int a, unsigned int b) {
  return a < b ? a : b;
}
__device__ __forceinline__ unsigned int umin3(unsigned int a, unsigned int b, unsigned int c) {
  return umin2(umin2(a, b), c);
}

// async global->LDS, 16B per lane; lds base must be wave-uniform
__device__ __forceinline__ void gload16(const void* gsrc, void* ldst) {
  __builtin_amdgcn_global_load_lds(
      (const __attribute__((address_space(1))) unsigned int*)gsrc,
      (__attribute__((address_space(3))) unsigned int*)ldst, 16, 0, 0);
}

// ---------------------------------------------------------------------------
// x[b][c][n] -> xt[b][n][c] (f32), xhi[b][n][c] (bf16), hsq[b][n] = 0.5*|x|^2
__launch_bounds__(256)
__global__ void k_split(const float* __restrict__ x,
                        float* __restrict__ xt,
                        unsigned short* __restrict__ xhi,
                        float* __restrict__ hsq) {
  __shared__ float Ls[CC][65];
  int b = blockIdx.x >> 6, nb = blockIdx.x & 63;
  int n0 = nb * 64;
  int tid = threadIdx.x;
  const float* xb = x + (size_t)b * CC * NN;

  for (int i = tid; i < CC * 64; i += 256) {
    int c = i >> 6, nl = i & 63;
    Ls[c][nl] = xb[(size_t)c * NN + n0 + nl];
  }
  __syncthreads();

  int n = tid >> 2, part = tid & 3;     // 64 n x 4 parts (32 c each)
  int node = b * NN + n0 + n;
  float sum = 0.f;
#pragma unroll
  for (int g = 0; g < 4; ++g) {
    float v[8];
    ushort8v ph;
#pragma unroll
    for (int j = 0; j < 8; ++j) {
      int c = part * 32 + g * 8 + j;
      v[j] = Ls[c][n];
      ph[j] = f2bf(v[j]);
      sum += v[j] * v[j];
    }
    float4 f0 = {v[0], v[1], v[2], v[3]};
    float4 f1 = {v[4], v[5], v[6], v[7]};
    *(float4*)&xt[(size_t)node * CC + part * 32 + g * 8] = f0;
    *(float4*)&xt[(size_t)node * CC + part * 32 + g * 8 + 4] = f1;
    *(ushort8v*)&xhi[(size_t)node * CC + part * 32 + g * 8] = ph;
  }
  sum += __shfl_xor(sum, 1, 64);
  sum += __shfl_xor(sum, 2, 64);
  if (part == 0) hsq[node] = 0.5f * sum;
}

// ---------------------------------------------------------------------------
// Pack W into h2's fragment order: granule g = ((ct*4+ks)*16 + r16)*4 + kg
// holds W[c0..c0+7][hf] (bf16 hi/lo) with hf = ct*16+r16, c0 = ks*32+kg*8.
// Consecutive lanes in k_h2 then read CONSECUTIVE granules (fully coalesced).
__global__ void k_wpack(const float* __restrict__ W,
                        unsigned short* __restrict__ Whi,
                        unsigned short* __restrict__ Wlo) {
  int g = blockIdx.x * 256 + threadIdx.x;   // 0..8191 granules
  int kg = g & 3, r16 = (g >> 2) & 15, ks = (g >> 6) & 3, ct = g >> 8;
  int hf = ct * 16 + r16;
  int c0 = ks * 32 + kg * 8;
  ushort8v ph, pl;
#pragma unroll
  for (int j = 0; j < 8; ++j) {
    float v = W[(size_t)(c0 + j) * HF + hf];
    unsigned short hb = f2bf(v);
    ph[j] = hb;
    pl[j] = f2bf(v - bf2f(hb));
  }
  *(ushort8v*)&Whi[(size_t)g * 8] = ph;
  *(ushort8v*)&Wlo[(size_t)g * 8] = pl;
}

// ---------------------------------------------------------------------------
// tau scan, split into 2 half-subset blocks per query group: each block scans
// 512 candidates (32 tiles) and writes per-query top-16 KEY VALUES to keys16.
// LDS-staged (double-buffered gload16, XOR swizzle); mv padded [65].
// XCD-pinned: batch = blockIdx & 7.
__launch_bounds__(256)
__global__ void k_tauscan(const unsigned short* __restrict__ xhi,
                          const float* __restrict__ hsq,
                          unsigned int* __restrict__ keys16) {
  __shared__ short8v AS[2][256];           // 8 KB staging (16 nodes x 16 granules)
  __shared__ unsigned int mv[4][16][65];   // 16.6 KB (padded: conflict-free dump)
  int bx = blockIdx.x;
  int b = bx & 7, rest = bx >> 3;          // XCD-pinned; rest 0..127
  int qg = rest >> 1, sh = rest & 1;       // scan-half
  int w = threadIdx.x >> 6, lane = threadIdx.x & 63;
  int qcol = lane & 15, kg = lane >> 4;
  int base = b * NN;
  int q = base + qg * 64 + w * 16 + qcol;
  int t0 = sh * 32;

  const short8v* XH = (const short8v*)xhi;   // granules: node*16 + ks*4 + kg
  short8v bh0 = XH[(size_t)q * 16 + kg];
  short8v bh1 = XH[(size_t)q * 16 + 4 + kg];
  short8v bh2 = XH[(size_t)q * 16 + 8 + kg];
  short8v bh3 = XH[(size_t)q * 16 + 12 + kg];

  int snode = w * 4 + (lane >> 4);
  int sgran = (lane & 15) ^ (snode & 15);

  gload16(xhi + ((size_t)(base + t0 * 16 + snode)) * 128 + sgran * 8, &AS[0][w * 64]);
  __syncthreads();

  unsigned int bd[16];
  unsigned int worst = 0;
  int cur = 0;

#pragma unroll 1
  for (int lt = 0; lt < 32; ++lt) {
    if (lt + 1 < 32)
      gload16(xhi + ((size_t)(base + (t0 + lt + 1) * 16 + snode)) * 128 + sgran * 8,
              &AS[cur ^ 1][w * 64]);
    short8v ah0 = AS[cur][qcol * 16 + ((0 + kg) ^ qcol)];
    short8v ah1 = AS[cur][qcol * 16 + ((4 + kg) ^ qcol)];
    short8v ah2 = AS[cur][qcol * 16 + ((8 + kg) ^ qcol)];
    short8v ah3 = AS[cur][qcol * 16 + ((12 + kg) ^ qcol)];
    f32x4 acc = {0.f, 0.f, 0.f, 0.f};
    acc = __builtin_amdgcn_mfma_f32_16x16x32_bf16(ah0, bh0, acc, 0, 0, 0);
    acc = __builtin_amdgcn_mfma_f32_16x16x32_bf16(ah1, bh1, acc, 0, 0, 0);
    acc = __builtin_amdgcn_mfma_f32_16x16x32_bf16(ah2, bh2, acc, 0, 0, 0);
    acc = __builtin_amdgcn_mfma_f32_16x16x32_bf16(ah3, bh3, acc, 0, 0, 0);
    float4 hs = *(const float4*)&hsq[base + (t0 + lt) * 16 + kg * 4];
    float hsa[4] = {hs.x, hs.y, hs.z, hs.w};

    if (lt < 4) {
#pragma unroll
      for (int r = 0; r < 4; ++r) {
        float tv = acc[r] - hsa[r] + 512.0f;
        bd[lt * 4 + r] = (__float_as_uint(tv) & ~1023u) | (1023u - (unsigned)(lt * 4 + r));
      }
      if (lt == 3) {
        unsigned int m0 = umin3(bd[0], bd[1], bd[2]);
        m0 = umin3(m0, bd[3], bd[4]);
        m0 = umin3(m0, bd[5], bd[6]);
        m0 = umin2(m0, bd[7]);
        unsigned int m1 = umin3(bd[8], bd[9], bd[10]);
        m1 = umin3(m1, bd[11], bd[12]);
        m1 = umin3(m1, bd[13], bd[14]);
        m1 = umin2(m1, bd[15]);
        worst = umin2(m0, m1);
      }
    } else {
#pragma unroll
      for (int r = 0; r < 4; ++r) {
        float tv = acc[r] - hsa[r] + 512.0f;
        unsigned int key = (__float_as_uint(tv) & ~1023u) | (1023u - (unsigned)(lt * 4 + r));
        if (key > worst) {
#pragma unroll
          for (int i = 0; i < 16; ++i) bd[i] = (bd[i] == worst) ? key : bd[i];
          unsigned int n0_ = umin3(bd[0], bd[1], bd[2]);
          n0_ = umin3(n0_, bd[3], bd[4]);
          n0_ = umin3(n0_, bd[5], bd[6]);
          n0_ = umin2(n0_, bd[7]);
          unsigned int n1_ = umin3(bd[8], bd[9], bd[10]);
          n1_ = umin3(n1_, bd[11], bd[12]);
          n1_ = umin3(n1_, bd[13], bd[14]);
          n1_ = umin2(n1_, bd[15]);
          worst = umin2(n0_, n1_);
        }
      }
    }
    __syncthreads();
    cur ^= 1;
  }

#pragma unroll
  for (int i = 0; i < 16; ++i) mv[w][qcol][kg * 16 + i] = bd[i];
  __syncthreads();

  if (lane < 16) {
    unsigned int tb[16];
#pragma unroll
    for (int i = 0; i < 16; ++i) tb[i] = mv[w][lane][i];
    unsigned int w0 = umin3(tb[0], tb[1], tb[2]);
    w0 = umin3(w0, tb[3], tb[4]);
    w0 = umin3(w0, tb[5], tb[6]);
    w0 = umin2(w0, tb[7]);
    unsigned int w1 = umin3(tb[8], tb[9], tb[10]);
    w1 = umin3(w1, tb[11], tb[12]);
    w1 = umin3(w1, tb[13], tb[14]);
    w1 = umin2(w1, tb[15]);
    unsigned int wst = umin2(w0, w1);
    for (int j = 16; j < 64; ++j) {
      unsigned int v = mv[w][lane][j];
      if (v > wst) {
        bool done = false;
#pragma unroll
        for (int i = 0; i < 16; ++i) {
          bool m = (!done) && (tb[i] == wst);
          done = done || m;
          tb[i] = m ? v : tb[i];
        }
        unsigned int a0 = umin3(tb[0], tb[1], tb[2]);
        a0 = umin3(a0, tb[3], tb[4]);
        a0 = umin3(a0, tb[5], tb[6]);
        a0 = umin2(a0, tb[7]);
        unsigned int a1 = umin3(tb[8], tb[9], tb[10]);
        a1 = umin3(a1, tb[11], tb[12]);
        a1 = umin3(a1, tb[13], tb[14]);
        a1 = umin2(a1, tb[15]);
        wst = umin2(a0, a1);
      }
    }
    int qq = base + qg * 64 + w * 16 + lane;
    unsigned int* o = keys16 + ((size_t)qq * 2 + sh) * 16;
#pragma unroll
    for (int i = 0; i < 16; ++i) o[i] = tb[i];
  }
}

// ---------------------------------------------------------------------------
// Merge per-half top-16 keys -> 16th-largest of union -> thr[q].
__launch_bounds__(256)
__global__ void k_taumerge(const unsigned int* __restrict__ keys16,
                           float* __restrict__ thr) {
  int q = blockIdx.x * 256 + threadIdx.x;
  const unsigned int* kp = keys16 + (size_t)q * 32;
  unsigned int tb[16];
#pragma unroll
  for (int i = 0; i < 16; ++i) tb[i] = kp[i];
  unsigned int w0 = umin3(tb[0], tb[1], tb[2]);
  w0 = umin3(w0, tb[3], tb[4]);
  w0 = umin3(w0, tb[5], tb[6]);
  w0 = umin2(w0, tb[7]);
  unsigned int w1 = umin3(tb[8], tb[9], tb[10]);
  w1 = umin3(w1, tb[11], tb[12]);
  w1 = umin3(w1, tb[13], tb[14]);
  w1 = umin2(w1, tb[15]);
  unsigned int wst = umin2(w0, w1);
#pragma unroll 1
  for (int j = 16; j < 32; ++j) {
    unsigned int v = kp[j];
    if (v > wst) {
      bool done = false;
#pragma unroll
      for (int i = 0; i < 16; ++i) {
        bool m = (!done) && (tb[i] == wst);
        done = done || m;
        tb[i] = m ? v : tb[i];
      }
      unsigned int a0 = umin3(tb[0], tb[1], tb[2]);
      a0 = umin3(a0, tb[3], tb[4]);
      a0 = umin3(a0, tb[5], tb[6]);
      a0 = umin2(a0, tb[7]);
      unsigned int a1 = umin3(tb[8], tb[9], tb[10]);
      a1 = umin3(a1, tb[11], tb[12]);
      a1 = umin3(a1, tb[13], tb[14]);
      a1 = umin2(a1, tb[15]);
      wst = umin2(a0, a1);
    }
  }
  thr[q] = __uint_as_float(wst & ~1023u) - 0.5f;
}

// ---------------------------------------------------------------------------
// Collect survivors (tv >= thr[q]): 2-tile-per-barrier LDS staging + PRIVATE
// per-lane LDS append lists (no ballot, no atomics), then 4-lane shfl-prefix
// merge into per-(query,half) global lists. XCD-pinned: batch = blockIdx & 7.
__launch_bounds__(256)
__global__ void k_collect2(const unsigned short* __restrict__ xhi,
                           const float* __restrict__ hsq,
                           const float* __restrict__ thr,
                           unsigned short* __restrict__ cand,
                           unsigned short* __restrict__ qcnt) {
  __shared__ short8v AS[2][2][256];          // 16 KB staging (2 bufs x 2 tiles)
  __shared__ unsigned short lbuf[256][34];   // 17 KB private lists (pad 34)
  int bx = blockIdx.x;
  int b = bx & 7, rest = bx >> 3;            // XCD-pinned batch; rest 0..127
  int qg = rest >> 1, ht = rest & 1;
  int w = threadIdx.x >> 6, lane = threadIdx.x & 63;
  int tid = threadIdx.x;
  int qcol = lane & 15, kg = lane >> 4;
  int base = b * NN;
  int q = base + qg * 64 + w * 16 + qcol;

  const short8v* XH = (const short8v*)xhi;
  short8v bh0 = XH[(size_t)q * 16 + kg];
  short8v bh1 = XH[(size_t)q * 16 + 4 + kg];
  short8v bh2 = XH[(size_t)q * 16 + 8 + kg];
  short8v bh3 = XH[(size_t)q * 16 + 12 + kg];
  float myThr = thr[q];

  int snode = w * 4 + (lane >> 4);
  int sgran = (lane & 15) ^ (snode & 15);

  int tbase = ht * 128;
  gload16(xhi + ((size_t)(base + (tbase + 0) * 16 + snode)) * 128 + sgran * 8,
          &AS[0][0][w * 64]);
  gload16(xhi + ((size_t)(base + (tbase + 1) * 16 + snode)) * 128 + sgran * 8,
          &AS[0][1][w * 64]);
  __syncthreads();

  int myCnt = 0;
  int cur = 0;

#pragma unroll 1
  for (int lt = 0; lt < 128; lt += 2) {
    if (lt + 2 < 128) {
      gload16(xhi + ((size_t)(base + (tbase + lt + 2) * 16 + snode)) * 128 + sgran * 8,
              &AS[cur ^ 1][0][w * 64]);
      gload16(xhi + ((size_t)(base + (tbase + lt + 3) * 16 + snode)) * 128 + sgran * 8,
              &AS[cur ^ 1][1][w * 64]);
    }
#pragma unroll
    for (int tt = 0; tt < 2; ++tt) {
      int t = tbase + lt + tt;
      short8v ah0 = AS[cur][tt][qcol * 16 + ((0 + kg) ^ qcol)];
      short8v ah1 = AS[cur][tt][qcol * 16 + ((4 + kg) ^ qcol)];
      short8v ah2 = AS[cur][tt][qcol * 16 + ((8 + kg) ^ qcol)];
      short8v ah3 = AS[cur][tt][qcol * 16 + ((12 + kg) ^ qcol)];
      f32x4 acc = {0.f, 0.f, 0.f, 0.f};
      acc = __builtin_amdgcn_mfma_f32_16x16x32_bf16(ah0, bh0, acc, 0, 0, 0);
      acc = __builtin_amdgcn_mfma_f32_16x16x32_bf16(ah1, bh1, acc, 0, 0, 0);
      acc = __builtin_amdgcn_mfma_f32_16x16x32_bf16(ah2, bh2, acc, 0, 0, 0);
      acc = __builtin_amdgcn_mfma_f32_16x16x32_bf16(ah3, bh3, acc, 0, 0, 0);
      float4 hs = *(const float4*)&hsq[base + t * 16 + kg * 4];
      float hsa[4] = {hs.x, hs.y, hs.z, hs.w};
#pragma unroll
      for (int r = 0; r < 4; ++r) {
        float tv = acc[r] - hsa[r] + 512.0f;
        bool pass = (tv >= myThr) && (myCnt < LCAP);
        if (pass) {
          lbuf[tid][myCnt] = (unsigned short)(t * 16 + kg * 4 + r);
          ++myCnt;
        }
      }
    }
    __syncthreads();
    cur ^= 1;
  }

  // merge: prefix over the 4 kg-lanes of this query (lanes qcol+16*kg)
  int c0_ = __shfl(myCnt, qcol, 64);
  int c1_ = __shfl(myCnt, qcol + 16, 64);
  int c2_ = __shfl(myCnt, qcol + 32, 64);
  int c3_ = __shfl(myCnt, qcol + 48, 64);
  int off = (kg > 0 ? c0_ : 0) + (kg > 1 ? c1_ : 0) + (kg > 2 ? c2_ : 0);
  int tot = c0_ + c1_ + c2_ + c3_;        // <= 4*LCAP = CAPH
  unsigned short* dst = cand + (size_t)q * (2 * CAPH) + ht * CAPH + off;
#pragma unroll 1
  for (int i = 0; i < myCnt; ++i) dst[i] = lbuf[tid][i];
  if (kg == 0) qcnt[(size_t)q * 2 + ht] = (unsigned short)tot;
}

// ---------------------------------------------------------------------------
// Exact f32 rerank, 8-lane cooperative dot phase; selection via per-lane
// sorted-4 lists + val-only butterfly argmax + ballot/ffs winner broadcast.
__launch_bounds__(256)
__global__ void k_rerank(const float* __restrict__ xt, const float* __restrict__ hsq,
                         const unsigned short* __restrict__ cand,
                         const unsigned short* __restrict__ qcnt,
                         unsigned short* __restrict__ nbr) {
  __shared__ float pv[4][256];
  int w = threadIdx.x >> 6;
  int bid = blockIdx.x;
  int b = bid & 7, inner = bid >> 3;      // XCD-pinned batch; inner 0..1023
  int wq = (b << 12) + inner * 4 + w;
  int lane = threadIdx.x & 63;
  int base = b * NN;
  int n0 = qcnt[(size_t)wq * 2];
  int n1 = qcnt[(size_t)wq * 2 + 1];
  int nt = n0 + n1;                       // <= 256
  const float* qr = xt + (size_t)wq * CC;
  int cid = lane >> 3, part = lane & 7;

  float4 qv[4];
#pragma unroll
  for (int ph = 0; ph < 4; ++ph)
    qv[ph] = *(const float4*)&qr[ph * 32 + part * 4];

  int npass = (nt + 7) >> 3;
#pragma unroll 2
  for (int p = 0; p < npass; ++p) {
    int j = p * 8 + cid;
    bool valid = j < nt;
    int c = 0;
    if (valid)
      c = (j < n0) ? cand[(size_t)wq * (2 * CAPH) + j]
                   : cand[(size_t)wq * (2 * CAPH) + CAPH + (j - n0)];
    const float* cr = xt + (size_t)(base + c) * CC;
    float acc = 0.f;
#pragma unroll
    for (int ph = 0; ph < 4; ++ph) {
      float4 cv = *(const float4*)&cr[ph * 32 + part * 4];
      acc = fmaf(qv[ph].x, cv.x, acc);
      acc = fmaf(qv[ph].y, cv.y, acc);
      acc = fmaf(qv[ph].z, cv.z, acc);
      acc = fmaf(qv[ph].w, cv.w, acc);
    }
    acc += __shfl_xor(acc, 1, 64);
    acc += __shfl_xor(acc, 2, 64);
    acc += __shfl_xor(acc, 4, 64);
    if (part == 0)
      pv[w][p * 8 + cid] = valid ? (acc - hsq[base + c]) : -3.4e38f;
  }

  float v0, v1, v2, v3;
  int i0, i1, i2, i3;
  {
    float tv[4]; int ti[4];
#pragma unroll
    for (int s = 0; s < 4; ++s) {
      int j = lane + s * 64;
      if (j < nt) {
        tv[s] = pv[w][j];
        ti[s] = (j < n0) ? cand[(size_t)wq * (2 * CAPH) + j]
                         : cand[(size_t)wq * (2 * CAPH) + CAPH + (j - n0)];
      } else {
        tv[s] = -3.4e38f; ti[s] = 0x7fffffff;
      }
    }
    v0 = tv[0]; v1 = tv[1]; v2 = tv[2]; v3 = tv[3];
    i0 = ti[0]; i1 = ti[1]; i2 = ti[2]; i3 = ti[3];
  }
#define CE(va, ia, vb, ib)                                        \
  {                                                               \
    bool sw_ = (vb > va) || (vb == va && ib < ia);                \
    float tv_ = va; int ti_ = ia;                                 \
    va = sw_ ? vb : va; ia = sw_ ? ib : ia;                       \
    vb = sw_ ? tv_ : vb; ib = sw_ ? ti_ : ib;                     \
  }
  CE(v0, i0, v1, i1); CE(v2, i2, v3, i3);
  CE(v0, i0, v2, i2); CE(v1, i1, v3, i3);
  CE(v1, i1, v2, i2);
#undef CE

  unsigned short* o = nbr + (size_t)wq * KK;
  for (int s = 0; s < KK; ++s) {
    float bv = v0;
#pragma unroll
    for (int off = 1; off < 64; off <<= 1)
      bv = fmaxf(bv, __shfl_xor(bv, off, 64));
    unsigned long long own = __ballot(v0 == bv);
    int wi;
    bool owner;
    if (__popcll(own) > 1) {           // exact-tie path (wave-uniform, rare)
      int ci = (v0 == bv) ? i0 : 0x7fffffff;
#pragma unroll
      for (int off = 1; off < 64; off <<= 1) {
        int oc = __shfl_xor(ci, off, 64);
        ci = oc < ci ? oc : ci;
      }
      wi = ci;
      owner = (v0 == bv) && (i0 == ci);
    } else {
      int first = (int)__ffsll((unsigned long long)own) - 1;
      wi = __shfl(i0, first, 64);
      owner = (lane == first);
    }
    if (lane == 0) o[s] = (unsigned short)wi;
    if (owner) {
      v0 = v1; i0 = i1;
      v1 = v2; i1 = i2;
      v2 = v3; i2 = i3;
      v3 = -3.4e38f; i3 = 0x7fffffff;
    }
  }
}

// ---------------------------------------------------------------------------
// h = xt . W via 3-term split-bf16 MFMA; W fragments in coalesced order
// (granule ((ct*4+ks)*16+r16)*4+kg -> consecutive lanes read consecutive 16B).
__launch_bounds__(256)
__global__ void k_h2(const float* __restrict__ xt,
                     const unsigned short* __restrict__ Whi,
                     const unsigned short* __restrict__ Wlo,
                     unsigned short* __restrict__ hout) {
  int w = threadIdx.x >> 6, lane = threadIdx.x & 63;
  int r16 = lane & 15, kg = lane >> 4;
  int nd0 = blockIdx.x * 64 + w * 16;
  const float* arow = xt + (size_t)(nd0 + r16) * CC;
  short8v ahi[4], alo[4];
#pragma unroll
  for (int ks = 0; ks < 4; ++ks) {
    float4 f0 = *(const float4*)&arow[ks * 32 + kg * 8];
    float4 f1 = *(const float4*)&arow[ks * 32 + kg * 8 + 4];
    float fv[8] = {f0.x, f0.y, f0.z, f0.w, f1.x, f1.y, f1.z, f1.w};
    short8v hh_, ll_;
#pragma unroll
    for (int j = 0; j < 8; ++j) {
      unsigned short hb = f2bf(fv[j]);
      hh_[j] = (short)hb;
      ll_[j] = (short)f2bf(fv[j] - bf2f(hb));
    }
    ahi[ks] = hh_; alo[ks] = ll_;
  }
  const short8v* WH = (const short8v*)Whi;
  const short8v* WL = (const short8v*)Wlo;
#pragma unroll 1
  for (int ct = 0; ct < 32; ++ct) {
    int hf = ct * 16 + r16;
    f32x4 acc = {0.f, 0.f, 0.f, 0.f};
#pragma unroll
    for (int ks = 0; ks < 4; ++ks) {
      size_t gidx = (size_t)(((ct * 4 + ks) * 16 + r16) * 4 + kg);
      short8v bh = WH[gidx];
      short8v bl = WL[gidx];
      acc = __builtin_amdgcn_mfma_f32_16x16x32_bf16(ahi[ks], bh, acc, 0, 0, 0);
      acc = __builtin_amdgcn_mfma_f32_16x16x32_bf16(ahi[ks], bl, acc, 0, 0, 0);
      acc = __builtin_amdgcn_mfma_f32_16x16x32_bf16(alo[ks], bh, acc, 0, 0, 0);
    }
#pragma unroll
    for (int r = 0; r < 4; ++r)
      hout[(size_t)(nd0 + kg * 4 + r) * HF + hf] = f2bf(acc[r]);
  }
}

// ---------------------------------------------------------------------------
// a_src/a_dst[b][n][h] = sum_f h[b][n][h][f] * att_{src,dst}[h][f]
__global__ void k_att(const unsigned short* __restrict__ h,
                      const float* __restrict__ att_src, const float* __restrict__ att_dst,
                      float* __restrict__ a_src, float* __restrict__ a_dst) {
  int gid = blockIdx.x * 256 + threadIdx.x;
  int wid = gid >> 6;            // node index b*N+n
  int lane = threadIdx.x & 63;
  uint4 v = ((const uint4*)(h + (size_t)wid * HF))[lane];
  float hv[8];
  hv[0] = bf2f(v.x & 0xffff); hv[1] = bf2f(v.x >> 16);
  hv[2] = bf2f(v.y & 0xffff); hv[3] = bf2f(v.y >> 16);
  hv[4] = bf2f(v.z & 0xffff); hv[5] = bf2f(v.z >> 16);
  hv[6] = bf2f(v.w & 0xffff); hv[7] = bf2f(v.w >> 16);
  int base = lane * 8;
  float s = 0.f, d = 0.f;
#pragma unroll
  for (int i = 0; i < 8; ++i) {
    s += hv[i] * att_src[base + i];
    d += hv[i] * att_dst[base + i];
  }
#pragma unroll
  for (int off = 1; off < 16; off <<= 1) {
    s += __shfl_xor(s, off, 64);
    d += __shfl_xor(d, off, 64);
  }
  if ((lane & 15) == 0) {
    int hh = lane >> 4;
    a_src[wid * HH + hh] = s;
    a_dst[wid * HH + hh] = d;
  }
}

// ---------------------------------------------------------------------------
// gather + softmax(k=16) + weighted sum + head-mean + bias + transpose store
// XCD-pinned: batch = blockIdx & 7 (h slab 4.2 MB/batch ~ L2-resident).
__launch_bounds__(256)
__global__ void k_out(const unsigned short* __restrict__ h,
                      const unsigned short* __restrict__ nbr,
                      const float* __restrict__ a_src, const float* __restrict__ a_dst,
                      const float* __restrict__ bias, float* __restrict__ out) {
  __shared__ float Ot[FF][17];
  int b = blockIdx.x & 7, nb = blockIdx.x >> 3;   // XCD-pinned batch; nb 0..255
  int w = threadIdx.x >> 6, lane = threadIdx.x & 63;
  int hh = lane >> 4, jj = lane & 15;

  for (int t = 0; t < 4; ++t) {
    int nl = w * 4 + t;
    int node = b * NN + nb * 16 + nl;
    int mj = nbr[node * KK + jj];

    float e = a_src[((size_t)b * NN + mj) * HH + hh] + a_dst[(size_t)node * HH + hh];
    e = e >= 0.f ? e : 0.2f * e;
    float m = e;
#pragma unroll
    for (int off = 1; off < 16; off <<= 1) m = fmaxf(m, __shfl_xor(m, off, 64));
    float p = expf(e - m);
    float sum = p;
#pragma unroll
    for (int off = 1; off < 16; off <<= 1) sum += __shfl_xor(sum, off, 64);
    float alpha = p / sum;

    float acc[8];
#pragma unroll
    for (int i = 0; i < 8; ++i) acc[i] = 0.f;

#pragma unroll
    for (int j = 0; j < 16; ++j) {
      float aj = __shfl(alpha, (hh << 4) | j, 64);
      int m2 = __shfl(mj, j, 64);
      uint4 v = ((const uint4*)(h + (size_t)(b * NN + m2) * HF))[lane];
      acc[0] += aj * bf2f(v.x & 0xffff); acc[1] += aj * bf2f(v.x >> 16);
      acc[2] += aj * bf2f(v.y & 0xffff); acc[3] += aj * bf2f(v.y >> 16);
      acc[4] += aj * bf2f(v.z & 0xffff); acc[5] += aj * bf2f(v.z >> 16);
      acc[6] += aj * bf2f(v.w & 0xffff); acc[7] += aj * bf2f(v.w >> 16);
    }

#pragma unroll
    for (int i = 0; i < 8; ++i) {
      acc[i] += __shfl_xor(acc[i], 16, 64);
      acc[i] += __shfl_xor(acc[i], 32, 64);
    }
    if (hh == 0) {
#pragma unroll
      for (int i = 0; i < 8; ++i) Ot[jj * 8 + i][nl] = acc[i] * 0.25f;
    }
  }
  __syncthreads();

#pragma unroll
  for (int it = 0; it < 8; ++it) {
    int idx = it * 256 + threadIdx.x;
    int f = idx >> 4, nl = idx & 15;
    out[((size_t)b * FF + f) * NN + nb * 16 + nl] = Ot[f][nl] + bias[f];
  }
}

// ---------------------------------------------------------------------------
extern "C" void kernel_launch(void* const* d_in, const int* in_sizes, int n_in,
                              void* d_out, int out_size, void* d_ws, size_t ws_size,
                              hipStream_t stream) {
  const float* x       = (const float*)d_in[0];
  const float* W       = (const float*)d_in[1];
  const float* att_src = (const float*)d_in[2];
  const float* att_dst = (const float*)d_in[3];
  const float* bias    = (const float*)d_in[4];

  char* ws = (char*)d_ws;
  // Lifetime-aliased layout (identical to R14, all sizes verified):
  //   [0        ,16777216): xt    f32 32768*128*4 = 16,777,216 — split..rerank,h2
  //   [16777216 ,25165824): xhi   bf16 32768*128*2 = 8,388,608 — split..collect2
  //   [25165824 ,30360128): keys16 u32 32768*32*4 = 4,194,304  — tauscan..taumerge
  //   [25165824 ,41943040): cand  u16 32768*256*2 = 16,777,216 — collect2..rerank
  //   [16777216 ,50331648): h     bf16 32768*512*2 = 33,554,432 — k_h2 AFTER rerank
  //   [50331648 ,51380224): nbr   u16 32768*16*2 = 1,048,576   — rerank..out
  //   [51380224 ,51511296): qcnt  u16 32768*2*2 = 131,072      — collect2..rerank
  //   [51511296 ,51642368): thr   f32 32768*4 = 131,072        — taumerge..collect2
  //   [51642368 ,51773440): hsq   f32 32768*4 = 131,072        — split..rerank
  //   [51773440 ,52297728): a_src f32 524,288 (aliased early by Whi+Wlo 2*131,072)
  //   [52297728 ,52822016): a_dst f32 524,288
  // total 52,822,016 B (proven envelope)
  float* xt            = (float*)ws;
  unsigned short* xhi  = (unsigned short*)(ws + 16777216);
  unsigned int* keys16 = (unsigned int*)(ws + 25165824);
  unsigned short* cand = (unsigned short*)(ws + 25165824);
  unsigned short* h    = (unsigned short*)(ws + 16777216);
  unsigned short* nbr  = (unsigned short*)(ws + 50331648);
  unsigned short* qcnt = (unsigned short*)(ws + 51380224);
  float* thr   = (float*)(ws + 51511296);
  float* hsq   = (float*)(ws + 51642368);
  float* a_src = (float*)(ws + 51773440);
  unsigned short* Whi  = (unsigned short*)(ws + 51773440);
  unsigned short* Wlo  = (unsigned short*)(ws + 51773440 + 131072);
  float* a_dst = (float*)(ws + 52297728);

  float* out = (float*)d_out;

  k_split   <<<BB * (NN / 64), 256, 0, stream>>>(x, xt, xhi, hsq);
  k_wpack   <<<HF * CC / 8 / 256, 256, 0, stream>>>(W, Whi, Wlo);
  k_tauscan <<<BB * 64 * 2, 256, 0, stream>>>(xhi, hsq, keys16);
  k_taumerge<<<BB * NN / 256, 256, 0, stream>>>(keys16, thr);
  k_collect2<<<BB * 64 * 2, 256, 0, stream>>>(xhi, hsq, thr, cand, qcnt);
  k_rerank  <<<BB * NN / 4, 256, 0, stream>>>(xt, hsq, cand, qcnt, nbr);
  k_h2      <<<BB * NN / 64, 256, 0, stream>>>(xt, Whi, Wlo, h);
  k_att     <<<BB * NN / 4, 256, 0, stream>>>(h, att_src, att_dst, a_src, a_dst);
  k_out     <<<BB * (NN / 16), 256, 0, stream>>>(h, nbr, a_src, a_dst, bias, out);
}

// Round 16
// 324.087 us; speedup vs baseline: 1.1665x; 1.0433x over previous
//
#include <hip/hip_runtime.h>
#include <hip/hip_bf16.h>

#define BB 8
#define CC 128
#define NN 4096
#define HH 4
#define FF 128
#define KK 16
#define HF 512      // H*F
#define CAPH 128    // survivor capacity per query per half (stride 256 total)
#define LCAP 32     // per-lane private survivor list cap (mu 8.75 + 7.9 sigma)

typedef __attribute__((ext_vector_type(8))) short short8v;
typedef __attribute__((ext_vector_type(8))) unsigned short ushort8v;
typedef __attribute__((ext_vector_type(4))) float f32x4;

__device__ __forceinline__ float bf2f(unsigned int u) {
  return __uint_as_float(u << 16);
}

__device__ __forceinline__ unsigned short f2bf(float f) {
  unsigned int u = __float_as_uint(f);
  unsigned int lsb = (u >> 16) & 1u;
  u += 0x7fffu + lsb;                 // RTNE
  return (unsigned short)(u >> 16);
}

__device__ __forceinline__ unsigned int umin2(unsigned int a, unsigned int b) {
  return a < b ? a : b;
}
__device__ __forceinline__ unsigned int umin3(unsigned int a, unsigned int b, unsigned int c) {
  return umin2(umin2(a, b), c);
}

// async global->LDS, 16B per lane; lds base must be wave-uniform
__device__ __forceinline__ void gload16(const void* gsrc, void* ldst) {
  __builtin_amdgcn_global_load_lds(
      (const __attribute__((address_space(1))) unsigned int*)gsrc,
      (__attribute__((address_space(3))) unsigned int*)ldst, 16, 0, 0);
}

// ---------------------------------------------------------------------------
// x[b][c][n] -> xt[b][n][c] (f32), xhi[b][n][c] (bf16), hsq[b][n] = 0.5*|x|^2
__launch_bounds__(256)
__global__ void k_split(const float* __restrict__ x,
                        float* __restrict__ xt,
                        unsigned short* __restrict__ xhi,
                        float* __restrict__ hsq) {
  __shared__ float Ls[CC][65];
  int b = blockIdx.x >> 6, nb = blockIdx.x & 63;
  int n0 = nb * 64;
  int tid = threadIdx.x;
  const float* xb = x + (size_t)b * CC * NN;

  for (int i = tid; i < CC * 64; i += 256) {
    int c = i >> 6, nl = i & 63;
    Ls[c][nl] = xb[(size_t)c * NN + n0 + nl];
  }
  __syncthreads();

  int n = tid >> 2, part = tid & 3;     // 64 n x 4 parts (32 c each)
  int node = b * NN + n0 + n;
  float sum = 0.f;
#pragma unroll
  for (int g = 0; g < 4; ++g) {
    float v[8];
    ushort8v ph;
#pragma unroll
    for (int j = 0; j < 8; ++j) {
      int c = part * 32 + g * 8 + j;
      v[j] = Ls[c][n];
      ph[j] = f2bf(v[j]);
      sum += v[j] * v[j];
    }
    float4 f0 = {v[0], v[1], v[2], v[3]};
    float4 f1 = {v[4], v[5], v[6], v[7]};
    *(float4*)&xt[(size_t)node * CC + part * 32 + g * 8] = f0;
    *(float4*)&xt[(size_t)node * CC + part * 32 + g * 8 + 4] = f1;
    *(ushort8v*)&xhi[(size_t)node * CC + part * 32 + g * 8] = ph;
  }
  sum += __shfl_xor(sum, 1, 64);
  sum += __shfl_xor(sum, 2, 64);
  if (part == 0) hsq[node] = 0.5f * sum;
}

// ---------------------------------------------------------------------------
// Pack W into h2's fragment order: granule g = ((ct*4+ks)*16 + r16)*4 + kg
__global__ void k_wpack(const float* __restrict__ W,
                        unsigned short* __restrict__ Whi,
                        unsigned short* __restrict__ Wlo) {
  int g = blockIdx.x * 256 + threadIdx.x;   // 0..8191 granules
  int kg = g & 3, r16 = (g >> 2) & 15, ks = (g >> 6) & 3, ct = g >> 8;
  int hf = ct * 16 + r16;
  int c0 = ks * 32 + kg * 8;
  ushort8v ph, pl;
#pragma unroll
  for (int j = 0; j < 8; ++j) {
    float v = W[(size_t)(c0 + j) * HF + hf];
    unsigned short hb = f2bf(v);
    ph[j] = hb;
    pl[j] = f2bf(v - bf2f(hb));
  }
  *(ushort8v*)&Whi[(size_t)g * 8] = ph;
  *(ushort8v*)&Wlo[(size_t)g * 8] = pl;
}

// ---------------------------------------------------------------------------
// tau scan, split into 2 half-subset blocks per query group (512 cands each);
// writes per-query top-16 KEY VALUES to keys16. XCD-pinned: batch = bx & 7.
__launch_bounds__(256)
__global__ void k_tauscan(const unsigned short* __restrict__ xhi,
                          const float* __restrict__ hsq,
                          unsigned int* __restrict__ keys16) {
  __shared__ short8v AS[2][256];           // 8 KB staging (16 nodes x 16 granules)
  __shared__ unsigned int mv[4][16][65];   // padded: conflict-free dump
  int bx = blockIdx.x;
  int b = bx & 7, rest = bx >> 3;          // XCD-pinned; rest 0..127
  int qg = rest >> 1, sh = rest & 1;       // scan-half
  int w = threadIdx.x >> 6, lane = threadIdx.x & 63;
  int qcol = lane & 15, kg = lane >> 4;
  int base = b * NN;
  int q = base + qg * 64 + w * 16 + qcol;
  int t0 = sh * 32;

  const short8v* XH = (const short8v*)xhi;   // granules: node*16 + ks*4 + kg
  short8v bh0 = XH[(size_t)q * 16 + kg];
  short8v bh1 = XH[(size_t)q * 16 + 4 + kg];
  short8v bh2 = XH[(size_t)q * 16 + 8 + kg];
  short8v bh3 = XH[(size_t)q * 16 + 12 + kg];

  int snode = w * 4 + (lane >> 4);
  int sgran = (lane & 15) ^ (snode & 15);

  gload16(xhi + ((size_t)(base + t0 * 16 + snode)) * 128 + sgran * 8, &AS[0][w * 64]);
  __syncthreads();

  unsigned int bd[16];
  unsigned int worst = 0;
  int cur = 0;

#pragma unroll 1
  for (int lt = 0; lt < 32; ++lt) {
    if (lt + 1 < 32)
      gload16(xhi + ((size_t)(base + (t0 + lt + 1) * 16 + snode)) * 128 + sgran * 8,
              &AS[cur ^ 1][w * 64]);
    short8v ah0 = AS[cur][qcol * 16 + ((0 + kg) ^ qcol)];
    short8v ah1 = AS[cur][qcol * 16 + ((4 + kg) ^ qcol)];
    short8v ah2 = AS[cur][qcol * 16 + ((8 + kg) ^ qcol)];
    short8v ah3 = AS[cur][qcol * 16 + ((12 + kg) ^ qcol)];
    f32x4 acc = {0.f, 0.f, 0.f, 0.f};
    acc = __builtin_amdgcn_mfma_f32_16x16x32_bf16(ah0, bh0, acc, 0, 0, 0);
    acc = __builtin_amdgcn_mfma_f32_16x16x32_bf16(ah1, bh1, acc, 0, 0, 0);
    acc = __builtin_amdgcn_mfma_f32_16x16x32_bf16(ah2, bh2, acc, 0, 0, 0);
    acc = __builtin_amdgcn_mfma_f32_16x16x32_bf16(ah3, bh3, acc, 0, 0, 0);
    float4 hs = *(const float4*)&hsq[base + (t0 + lt) * 16 + kg * 4];
    float hsa[4] = {hs.x, hs.y, hs.z, hs.w};

    if (lt < 4) {
#pragma unroll
      for (int r = 0; r < 4; ++r) {
        float tv = acc[r] - hsa[r] + 512.0f;
        bd[lt * 4 + r] = (__float_as_uint(tv) & ~1023u) | (1023u - (unsigned)(lt * 4 + r));
      }
      if (lt == 3) {
        unsigned int m0 = umin3(bd[0], bd[1], bd[2]);
        m0 = umin3(m0, bd[3], bd[4]);
        m0 = umin3(m0, bd[5], bd[6]);
        m0 = umin2(m0, bd[7]);
        unsigned int m1 = umin3(bd[8], bd[9], bd[10]);
        m1 = umin3(m1, bd[11], bd[12]);
        m1 = umin3(m1, bd[13], bd[14]);
        m1 = umin2(m1, bd[15]);
        worst = umin2(m0, m1);
      }
    } else {
#pragma unroll
      for (int r = 0; r < 4; ++r) {
        float tv = acc[r] - hsa[r] + 512.0f;
        unsigned int key = (__float_as_uint(tv) & ~1023u) | (1023u - (unsigned)(lt * 4 + r));
        if (key > worst) {
#pragma unroll
          for (int i = 0; i < 16; ++i) bd[i] = (bd[i] == worst) ? key : bd[i];
          unsigned int n0_ = umin3(bd[0], bd[1], bd[2]);
          n0_ = umin3(n0_, bd[3], bd[4]);
          n0_ = umin3(n0_, bd[5], bd[6]);
          n0_ = umin2(n0_, bd[7]);
          unsigned int n1_ = umin3(bd[8], bd[9], bd[10]);
          n1_ = umin3(n1_, bd[11], bd[12]);
          n1_ = umin3(n1_, bd[13], bd[14]);
          n1_ = umin2(n1_, bd[15]);
          worst = umin2(n0_, n1_);
        }
      }
    }
    __syncthreads();
    cur ^= 1;
  }

#pragma unroll
  for (int i = 0; i < 16; ++i) mv[w][qcol][kg * 16 + i] = bd[i];
  __syncthreads();

  if (lane < 16) {
    unsigned int tb[16];
#pragma unroll
    for (int i = 0; i < 16; ++i) tb[i] = mv[w][lane][i];
    unsigned int w0 = umin3(tb[0], tb[1], tb[2]);
    w0 = umin3(w0, tb[3], tb[4]);
    w0 = umin3(w0, tb[5], tb[6]);
    w0 = umin2(w0, tb[7]);
    unsigned int w1 = umin3(tb[8], tb[9], tb[10]);
    w1 = umin3(w1, tb[11], tb[12]);
    w1 = umin3(w1, tb[13], tb[14]);
    w1 = umin2(w1, tb[15]);
    unsigned int wst = umin2(w0, w1);
    for (int j = 16; j < 64; ++j) {
      unsigned int v = mv[w][lane][j];
      if (v > wst) {
        bool done = false;
#pragma unroll
        for (int i = 0; i < 16; ++i) {
          bool m = (!done) && (tb[i] == wst);
          done = done || m;
          tb[i] = m ? v : tb[i];
        }
        unsigned int a0 = umin3(tb[0], tb[1], tb[2]);
        a0 = umin3(a0, tb[3], tb[4]);
        a0 = umin3(a0, tb[5], tb[6]);
        a0 = umin2(a0, tb[7]);
        unsigned int a1 = umin3(tb[8], tb[9], tb[10]);
        a1 = umin3(a1, tb[11], tb[12]);
        a1 = umin3(a1, tb[13], tb[14]);
        a1 = umin2(a1, tb[15]);
        wst = umin2(a0, a1);
      }
    }
    int qq = base + qg * 64 + w * 16 + lane;
    unsigned int* o = keys16 + ((size_t)qq * 2 + sh) * 16;
#pragma unroll
    for (int i = 0; i < 16; ++i) o[i] = tb[i];
  }
}

// ---------------------------------------------------------------------------
// Merge per-half top-16 keys -> 16th-largest of union -> thr[q].
__launch_bounds__(256)
__global__ void k_taumerge(const unsigned int* __restrict__ keys16,
                           float* __restrict__ thr) {
  int q = blockIdx.x * 256 + threadIdx.x;
  const unsigned int* kp = keys16 + (size_t)q * 32;
  unsigned int tb[16];
#pragma unroll
  for (int i = 0; i < 16; ++i) tb[i] = kp[i];
  unsigned int w0 = umin3(tb[0], tb[1], tb[2]);
  w0 = umin3(w0, tb[3], tb[4]);
  w0 = umin3(w0, tb[5], tb[6]);
  w0 = umin2(w0, tb[7]);
  unsigned int w1 = umin3(tb[8], tb[9], tb[10]);
  w1 = umin3(w1, tb[11], tb[12]);
  w1 = umin3(w1, tb[13], tb[14]);
  w1 = umin2(w1, tb[15]);
  unsigned int wst = umin2(w0, w1);
#pragma unroll 1
  for (int j = 16; j < 32; ++j) {
    unsigned int v = kp[j];
    if (v > wst) {
      bool done = false;
#pragma unroll
      for (int i = 0; i < 16; ++i) {
        bool m = (!done) && (tb[i] == wst);
        done = done || m;
        tb[i] = m ? v : tb[i];
      }
      unsigned int a0 = umin3(tb[0], tb[1], tb[2]);
      a0 = umin3(a0, tb[3], tb[4]);
      a0 = umin3(a0, tb[5], tb[6]);
      a0 = umin2(a0, tb[7]);
      unsigned int a1 = umin3(tb[8], tb[9], tb[10]);
      a1 = umin3(a1, tb[11], tb[12]);
      a1 = umin3(a1, tb[13], tb[14]);
      a1 = umin2(a1, tb[15]);
      wst = umin2(a0, a1);
    }
  }
  thr[q] = __uint_as_float(wst & ~1023u) - 0.5f;
}

// ---------------------------------------------------------------------------
// Collect survivors (tv >= thr[q]): 2-tile-per-barrier LDS staging + PRIVATE
// per-lane LDS append lists, 4-lane shfl-prefix merge. XCD-pinned.
__launch_bounds__(256)
__global__ void k_collect2(const unsigned short* __restrict__ xhi,
                           const float* __restrict__ hsq,
                           const float* __restrict__ thr,
                           unsigned short* __restrict__ cand,
                           unsigned short* __restrict__ qcnt) {
  __shared__ short8v AS[2][2][256];          // 16 KB staging (2 bufs x 2 tiles)
  __shared__ unsigned short lbuf[256][34];   // 17 KB private lists (pad 34)
  int bx = blockIdx.x;
  int b = bx & 7, rest = bx >> 3;            // XCD-pinned batch; rest 0..127
  int qg = rest >> 1, ht = rest & 1;
  int w = threadIdx.x >> 6, lane = threadIdx.x & 63;
  int tid = threadIdx.x;
  int qcol = lane & 15, kg = lane >> 4;
  int base = b * NN;
  int q = base + qg * 64 + w * 16 + qcol;

  const short8v* XH = (const short8v*)xhi;
  short8v bh0 = XH[(size_t)q * 16 + kg];
  short8v bh1 = XH[(size_t)q * 16 + 4 + kg];
  short8v bh2 = XH[(size_t)q * 16 + 8 + kg];
  short8v bh3 = XH[(size_t)q * 16 + 12 + kg];
  float myThr = thr[q];

  int snode = w * 4 + (lane >> 4);
  int sgran = (lane & 15) ^ (snode & 15);

  int tbase = ht * 128;
  gload16(xhi + ((size_t)(base + (tbase + 0) * 16 + snode)) * 128 + sgran * 8,
          &AS[0][0][w * 64]);
  gload16(xhi + ((size_t)(base + (tbase + 1) * 16 + snode)) * 128 + sgran * 8,
          &AS[0][1][w * 64]);
  __syncthreads();

  int myCnt = 0;
  int cur = 0;

#pragma unroll 1
  for (int lt = 0; lt < 128; lt += 2) {
    if (lt + 2 < 128) {
      gload16(xhi + ((size_t)(base + (tbase + lt + 2) * 16 + snode)) * 128 + sgran * 8,
              &AS[cur ^ 1][0][w * 64]);
      gload16(xhi + ((size_t)(base + (tbase + lt + 3) * 16 + snode)) * 128 + sgran * 8,
              &AS[cur ^ 1][1][w * 64]);
    }
#pragma unroll
    for (int tt = 0; tt < 2; ++tt) {
      int t = tbase + lt + tt;
      short8v ah0 = AS[cur][tt][qcol * 16 + ((0 + kg) ^ qcol)];
      short8v ah1 = AS[cur][tt][qcol * 16 + ((4 + kg) ^ qcol)];
      short8v ah2 = AS[cur][tt][qcol * 16 + ((8 + kg) ^ qcol)];
      short8v ah3 = AS[cur][tt][qcol * 16 + ((12 + kg) ^ qcol)];
      f32x4 acc = {0.f, 0.f, 0.f, 0.f};
      acc = __builtin_amdgcn_mfma_f32_16x16x32_bf16(ah0, bh0, acc, 0, 0, 0);
      acc = __builtin_amdgcn_mfma_f32_16x16x32_bf16(ah1, bh1, acc, 0, 0, 0);
      acc = __builtin_amdgcn_mfma_f32_16x16x32_bf16(ah2, bh2, acc, 0, 0, 0);
      acc = __builtin_amdgcn_mfma_f32_16x16x32_bf16(ah3, bh3, acc, 0, 0, 0);
      float4 hs = *(const float4*)&hsq[base + t * 16 + kg * 4];
      float hsa[4] = {hs.x, hs.y, hs.z, hs.w};
#pragma unroll
      for (int r = 0; r < 4; ++r) {
        float tv = acc[r] - hsa[r] + 512.0f;
        bool pass = (tv >= myThr) && (myCnt < LCAP);
        if (pass) {
          lbuf[tid][myCnt] = (unsigned short)(t * 16 + kg * 4 + r);
          ++myCnt;
        }
      }
    }
    __syncthreads();
    cur ^= 1;
  }

  // merge: prefix over the 4 kg-lanes of this query (lanes qcol+16*kg)
  int c0_ = __shfl(myCnt, qcol, 64);
  int c1_ = __shfl(myCnt, qcol + 16, 64);
  int c2_ = __shfl(myCnt, qcol + 32, 64);
  int c3_ = __shfl(myCnt, qcol + 48, 64);
  int off = (kg > 0 ? c0_ : 0) + (kg > 1 ? c1_ : 0) + (kg > 2 ? c2_ : 0);
  int tot = c0_ + c1_ + c2_ + c3_;        // <= 4*LCAP = CAPH
  unsigned short* dst = cand + (size_t)q * (2 * CAPH) + ht * CAPH + off;
#pragma unroll 1
  for (int i = 0; i < myCnt; ++i) dst[i] = lbuf[tid][i];
  if (kg == 0) qcnt[(size_t)q * 2 + ht] = (unsigned short)tot;
}

// ---------------------------------------------------------------------------
// Exact f32 rerank, 8-lane cooperative dot phase; selection via sortable
// 64-bit keys in LDS + rank-by-broadcast-scan (no cross-lane shuffles):
// key = (sortbits(val)<<16) | (65535-idx); strict > == (val desc, idx asc).
// rank(slot) = #{j : key_j > key_slot}; ranks unique; rank<16 -> nbr[rank]=idx.
__launch_bounds__(256)
__global__ void k_rerank(const float* __restrict__ xt, const float* __restrict__ hsq,
                         const unsigned short* __restrict__ cand,
                         const unsigned short* __restrict__ qcnt,
                         unsigned short* __restrict__ nbr) {
  __shared__ unsigned long long pk[4][256];   // 8 KB sortable keys
  int w = threadIdx.x >> 6;
  int bid = blockIdx.x;
  int b = bid & 7, inner = bid >> 3;      // XCD-pinned batch; inner 0..1023
  int wq = (b << 12) + inner * 4 + w;
  int lane = threadIdx.x & 63;
  int base = b * NN;
  int n0 = qcnt[(size_t)wq * 2];
  int n1 = qcnt[(size_t)wq * 2 + 1];
  int nt = n0 + n1;                       // <= 256, >= 16
  const float* qr = xt + (size_t)wq * CC;
  int cid = lane >> 3, part = lane & 7;

  float4 qv[4];
#pragma unroll
  for (int ph = 0; ph < 4; ++ph)
    qv[ph] = *(const float4*)&qr[ph * 32 + part * 4];

  int npass = (nt + 7) >> 3;
#pragma unroll 2
  for (int p = 0; p < npass; ++p) {
    int j = p * 8 + cid;
    bool valid = j < nt;
    int c = 0;
    if (valid)
      c = (j < n0) ? cand[(size_t)wq * (2 * CAPH) + j]
                   : cand[(size_t)wq * (2 * CAPH) + CAPH + (j - n0)];
    const float* cr = xt + (size_t)(base + c) * CC;
    float acc = 0.f;
#pragma unroll
    for (int ph = 0; ph < 4; ++ph) {
      float4 cv = *(const float4*)&cr[ph * 32 + part * 4];
      acc = fmaf(qv[ph].x, cv.x, acc);
      acc = fmaf(qv[ph].y, cv.y, acc);
      acc = fmaf(qv[ph].z, cv.z, acc);
      acc = fmaf(qv[ph].w, cv.w, acc);
    }
    acc += __shfl_xor(acc, 1, 64);
    acc += __shfl_xor(acc, 2, 64);
    acc += __shfl_xor(acc, 4, 64);
    if (part == 0) {
      float val = acc - hsq[base + c];
      unsigned int sb = __float_as_uint(val);
      sb = (sb & 0x80000000u) ? ~sb : (sb | 0x80000000u);   // sortable bits
      unsigned long long key =
          ((unsigned long long)sb << 16) | (unsigned long long)(65535 - c);
      pk[w][p * 8 + cid] = valid ? key : 0ull;
    }
  }

  // load my slots
  unsigned long long sk[4];
#pragma unroll
  for (int s = 0; s < 4; ++s) {
    int j = lane + s * 64;
    sk[s] = (j < nt) ? pk[w][j] : 0ull;
  }

  int rk0 = 0, rk1 = 0, rk2 = 0, rk3 = 0;
  int nslot = (nt + 63) >> 6;             // wave-uniform 1..4
  if (nslot == 1) {
#pragma unroll 4
    for (int j = 0; j < nt; ++j) {
      unsigned long long kj = pk[w][j];
      rk0 += (kj > sk[0]);
    }
  } else if (nslot == 2) {
#pragma unroll 4
    for (int j = 0; j < nt; ++j) {
      unsigned long long kj = pk[w][j];
      rk0 += (kj > sk[0]);
      rk1 += (kj > sk[1]);
    }
  } else {
#pragma unroll 2
    for (int j = 0; j < nt; ++j) {
      unsigned long long kj = pk[w][j];
      rk0 += (kj > sk[0]);
      rk1 += (kj > sk[1]);
      rk2 += (kj > sk[2]);
      rk3 += (kj > sk[3]);
    }
  }

  unsigned short* o = nbr + (size_t)wq * KK;
  {
    int j = lane;
    if (j < nt && rk0 < KK) o[rk0] = (unsigned short)(65535 - (unsigned)(sk[0] & 0xffffull));
    j = lane + 64;
    if (j < nt && rk1 < KK) o[rk1] = (unsigned short)(65535 - (unsigned)(sk[1] & 0xffffull));
    j = lane + 128;
    if (j < nt && rk2 < KK) o[rk2] = (unsigned short)(65535 - (unsigned)(sk[2] & 0xffffull));
    j = lane + 192;
    if (j < nt && rk3 < KK) o[rk3] = (unsigned short)(65535 - (unsigned)(sk[3] & 0xffffull));
  }
}

// ---------------------------------------------------------------------------
// h = xt . W via 3-term split-bf16 MFMA; W fragments in coalesced order.
__launch_bounds__(256)
__global__ void k_h2(const float* __restrict__ xt,
                     const unsigned short* __restrict__ Whi,
                     const unsigned short* __restrict__ Wlo,
                     unsigned short* __restrict__ hout) {
  int w = threadIdx.x >> 6, lane = threadIdx.x & 63;
  int r16 = lane & 15, kg = lane >> 4;
  int nd0 = blockIdx.x * 64 + w * 16;
  const float* arow = xt + (size_t)(nd0 + r16) * CC;
  short8v ahi[4], alo[4];
#pragma unroll
  for (int ks = 0; ks < 4; ++ks) {
    float4 f0 = *(const float4*)&arow[ks * 32 + kg * 8];
    float4 f1 = *(const float4*)&arow[ks * 32 + kg * 8 + 4];
    float fv[8] = {f0.x, f0.y, f0.z, f0.w, f1.x, f1.y, f1.z, f1.w};
    short8v hh_, ll_;
#pragma unroll
    for (int j = 0; j < 8; ++j) {
      unsigned short hb = f2bf(fv[j]);
      hh_[j] = (short)hb;
      ll_[j] = (short)f2bf(fv[j] - bf2f(hb));
    }
    ahi[ks] = hh_; alo[ks] = ll_;
  }
  const short8v* WH = (const short8v*)Whi;
  const short8v* WL = (const short8v*)Wlo;
#pragma unroll 1
  for (int ct = 0; ct < 32; ++ct) {
    int hf = ct * 16 + r16;
    f32x4 acc = {0.f, 0.f, 0.f, 0.f};
#pragma unroll
    for (int ks = 0; ks < 4; ++ks) {
      size_t gidx = (size_t)(((ct * 4 + ks) * 16 + r16) * 4 + kg);
      short8v bh = WH[gidx];
      short8v bl = WL[gidx];
      acc = __builtin_amdgcn_mfma_f32_16x16x32_bf16(ahi[ks], bh, acc, 0, 0, 0);
      acc = __builtin_amdgcn_mfma_f32_16x16x32_bf16(ahi[ks], bl, acc, 0, 0, 0);
      acc = __builtin_amdgcn_mfma_f32_16x16x32_bf16(alo[ks], bh, acc, 0, 0, 0);
    }
#pragma unroll
    for (int r = 0; r < 4; ++r)
      hout[(size_t)(nd0 + kg * 4 + r) * HF + hf] = f2bf(acc[r]);
  }
}

// ---------------------------------------------------------------------------
// a_src/a_dst[b][n][h] = sum_f h[b][n][h][f] * att_{src,dst}[h][f]
__global__ void k_att(const unsigned short* __restrict__ h,
                      const float* __restrict__ att_src, const float* __restrict__ att_dst,
                      float* __restrict__ a_src, float* __restrict__ a_dst) {
  int gid = blockIdx.x * 256 + threadIdx.x;
  int wid = gid >> 6;            // node index b*N+n
  int lane = threadIdx.x & 63;
  uint4 v = ((const uint4*)(h + (size_t)wid * HF))[lane];
  float hv[8];
  hv[0] = bf2f(v.x & 0xffff); hv[1] = bf2f(v.x >> 16);
  hv[2] = bf2f(v.y & 0xffff); hv[3] = bf2f(v.y >> 16);
  hv[4] = bf2f(v.z & 0xffff); hv[5] = bf2f(v.z >> 16);
  hv[6] = bf2f(v.w & 0xffff); hv[7] = bf2f(v.w >> 16);
  int base = lane * 8;
  float s = 0.f, d = 0.f;
#pragma unroll
  for (int i = 0; i < 8; ++i) {
    s += hv[i] * att_src[base + i];
    d += hv[i] * att_dst[base + i];
  }
#pragma unroll
  for (int off = 1; off < 16; off <<= 1) {
    s += __shfl_xor(s, off, 64);
    d += __shfl_xor(d, off, 64);
  }
  if ((lane & 15) == 0) {
    int hh = lane >> 4;
    a_src[wid * HH + hh] = s;
    a_dst[wid * HH + hh] = d;
  }
}

// ---------------------------------------------------------------------------
// gather + softmax(k=16) + weighted sum + head-mean + bias + transpose store
// XCD-pinned: batch = blockIdx & 7.
__launch_bounds__(256)
__global__ void k_out(const unsigned short* __restrict__ h,
                      const unsigned short* __restrict__ nbr,
                      const float* __restrict__ a_src, const float* __restrict__ a_dst,
                      const float* __restrict__ bias, float* __restrict__ out) {
  __shared__ float Ot[FF][17];
  int b = blockIdx.x & 7, nb = blockIdx.x >> 3;   // XCD-pinned batch; nb 0..255
  int w = threadIdx.x >> 6, lane = threadIdx.x & 63;
  int hh = lane >> 4, jj = lane & 15;

  for (int t = 0; t < 4; ++t) {
    int nl = w * 4 + t;
    int node = b * NN + nb * 16 + nl;
    int mj = nbr[node * KK + jj];

    float e = a_src[((size_t)b * NN + mj) * HH + hh] + a_dst[(size_t)node * HH + hh];
    e = e >= 0.f ? e : 0.2f * e;
    float m = e;
#pragma unroll
    for (int off = 1; off < 16; off <<= 1) m = fmaxf(m, __shfl_xor(m, off, 64));
    float p = expf(e - m);
    float sum = p;
#pragma unroll
    for (int off = 1; off < 16; off <<= 1) sum += __shfl_xor(sum, off, 64);
    float alpha = p / sum;

    float acc[8];
#pragma unroll
    for (int i = 0; i < 8; ++i) acc[i] = 0.f;

#pragma unroll
    for (int j = 0; j < 16; ++j) {
      float aj = __shfl(alpha, (hh << 4) | j, 64);
      int m2 = __shfl(mj, j, 64);
      uint4 v = ((const uint4*)(h + (size_t)(b * NN + m2) * HF))[lane];
      acc[0] += aj * bf2f(v.x & 0xffff); acc[1] += aj * bf2f(v.x >> 16);
      acc[2] += aj * bf2f(v.y & 0xffff); acc[3] += aj * bf2f(v.y >> 16);
      acc[4] += aj * bf2f(v.z & 0xffff); acc[5] += aj * bf2f(v.z >> 16);
      acc[6] += aj * bf2f(v.w & 0xffff); acc[7] += aj * bf2f(v.w >> 16);
    }

#pragma unroll
    for (int i = 0; i < 8; ++i) {
      acc[i] += __shfl_xor(acc[i], 16, 64);
      acc[i] += __shfl_xor(acc[i], 32, 64);
    }
    if (hh == 0) {
#pragma unroll
      for (int i = 0; i < 8; ++i) Ot[jj * 8 + i][nl] = acc[i] * 0.25f;
    }
  }
  __syncthreads();

#pragma unroll
  for (int it = 0; it < 8; ++it) {
    int idx = it * 256 + threadIdx.x;
    int f = idx >> 4, nl = idx & 15;
    out[((size_t)b * FF + f) * NN + nb * 16 + nl] = Ot[f][nl] + bias[f];
  }
}

// ---------------------------------------------------------------------------
extern "C" void kernel_launch(void* const* d_in, const int* in_sizes, int n_in,
                              void* d_out, int out_size, void* d_ws, size_t ws_size,
                              hipStream_t stream) {
  const float* x       = (const float*)d_in[0];
  const float* W       = (const float*)d_in[1];
  const float* att_src = (const float*)d_in[2];
  const float* att_dst = (const float*)d_in[3];
  const float* bias    = (const float*)d_in[4];

  char* ws = (char*)d_ws;
  // Lifetime-aliased layout (identical to R15, all sizes verified):
  //   [0        ,16777216): xt    f32 32768*128*4 = 16,777,216 — split..rerank,h2
  //   [16777216 ,25165824): xhi   bf16 32768*128*2 = 8,388,608 — split..collect2
  //   [25165824 ,30360128): keys16 u32 32768*32*4 = 4,194,304  — tauscan..taumerge
  //   [25165824 ,41943040): cand  u16 32768*256*2 = 16,777,216 — collect2..rerank
  //   [16777216 ,50331648): h     bf16 32768*512*2 = 33,554,432 — k_h2 AFTER rerank
  //   [50331648 ,51380224): nbr   u16 32768*16*2 = 1,048,576   — rerank..out
  //   [51380224 ,51511296): qcnt  u16 32768*2*2 = 131,072      — collect2..rerank
  //   [51511296 ,51642368): thr   f32 32768*4 = 131,072        — taumerge..collect2
  //   [51642368 ,51773440): hsq   f32 32768*4 = 131,072        — split..rerank
  //   [51773440 ,52297728): a_src f32 524,288 (aliased early by Whi+Wlo 2*131,072)
  //   [52297728 ,52822016): a_dst f32 524,288
  // total 52,822,016 B (proven envelope)
  float* xt            = (float*)ws;
  unsigned short* xhi  = (unsigned short*)(ws + 16777216);
  unsigned int* keys16 = (unsigned int*)(ws + 25165824);
  unsigned short* cand = (unsigned short*)(ws + 25165824);
  unsigned short* h    = (unsigned short*)(ws + 16777216);
  unsigned short* nbr  = (unsigned short*)(ws + 50331648);
  unsigned short* qcnt = (unsigned short*)(ws + 51380224);
  float* thr   = (float*)(ws + 51511296);
  float* hsq   = (float*)(ws + 51642368);
  float* a_src = (float*)(ws + 51773440);
  unsigned short* Whi  = (unsigned short*)(ws + 51773440);
  unsigned short* Wlo  = (unsigned short*)(ws + 51773440 + 131072);
  float* a_dst = (float*)(ws + 52297728);

  float* out = (float*)d_out;

  k_split   <<<BB * (NN / 64), 256, 0, stream>>>(x, xt, xhi, hsq);
  k_wpack   <<<HF * CC / 8 / 256, 256, 0, stream>>>(W, Whi, Wlo);
  k_tauscan <<<BB * 64 * 2, 256, 0, stream>>>(xhi, hsq, keys16);
  k_taumerge<<<BB * NN / 256, 256, 0, stream>>>(keys16, thr);
  k_collect2<<<BB * 64 * 2, 256, 0, stream>>>(xhi, hsq, thr, cand, qcnt);
  k_rerank  <<<BB * NN / 4, 256, 0, stream>>>(xt, hsq, cand, qcnt, nbr);
  k_h2      <<<BB * NN / 64, 256, 0, stream>>>(xt, Whi, Wlo, h);
  k_att     <<<BB * NN / 4, 256, 0, stream>>>(h, att_src, att_dst, a_src, a_dst);
  k_out     <<<BB * (NN / 16), 256, 0, stream>>>(h, nbr, a_src, a_dst, bias, out);
}

// Round 17
// 292.541 us; speedup vs baseline: 1.2923x; 1.1078x over previous
//
#include <hip/hip_runtime.h>
#include <hip/hip_bf16.h>

#define BB 8
#define CC 128
#define NN 4096
#define HH 4
#define FF 128
#define KK 16
#define HF 512      // H*F
#define CAPH 128    // survivor capacity per query per half (stride 256 total)
#define LCAP 32     // per-lane private survivor list cap (mu 8.75 + 7.9 sigma)

typedef __attribute__((ext_vector_type(8))) short short8v;
typedef __attribute__((ext_vector_type(8))) unsigned short ushort8v;
typedef __attribute__((ext_vector_type(4))) float f32x4;

__device__ __forceinline__ float bf2f(unsigned int u) {
  return __uint_as_float(u << 16);
}

__device__ __forceinline__ unsigned short f2bf(float f) {
  unsigned int u = __float_as_uint(f);
  unsigned int lsb = (u >> 16) & 1u;
  u += 0x7fffu + lsb;                 // RTNE
  return (unsigned short)(u >> 16);
}

__device__ __forceinline__ unsigned int umin2(unsigned int a, unsigned int b) {
  return a < b ? a : b;
}
__device__ __forceinline__ unsigned int umin3(unsigned int a, unsigned int b, unsigned int c) {
  return umin2(umin2(a, b), c);
}

// async global->LDS, 16B per lane; lds base must be wave-uniform
__device__ __forceinline__ void gload16(const void* gsrc, void* ldst) {
  __builtin_amdgcn_global_load_lds(
      (const __attribute__((address_space(1))) unsigned int*)gsrc,
      (__attribute__((address_space(3))) unsigned int*)ldst, 16, 0, 0);
}

// ---------------------------------------------------------------------------
// x[b][c][n] -> xt[b][n][c] (f32), xhi[b][n][c] (bf16), hsq[b][n] = 0.5*|x|^2
__launch_bounds__(256)
__global__ void k_split(const float* __restrict__ x,
                        float* __restrict__ xt,
                        unsigned short* __restrict__ xhi,
                        float* __restrict__ hsq) {
  __shared__ float Ls[CC][65];
  int b = blockIdx.x >> 6, nb = blockIdx.x & 63;
  int n0 = nb * 64;
  int tid = threadIdx.x;
  const float* xb = x + (size_t)b * CC * NN;

  for (int i = tid; i < CC * 64; i += 256) {
    int c = i >> 6, nl = i & 63;
    Ls[c][nl] = xb[(size_t)c * NN + n0 + nl];
  }
  __syncthreads();

  int n = tid >> 2, part = tid & 3;     // 64 n x 4 parts (32 c each)
  int node = b * NN + n0 + n;
  float sum = 0.f;
#pragma unroll
  for (int g = 0; g < 4; ++g) {
    float v[8];
    ushort8v ph;
#pragma unroll
    for (int j = 0; j < 8; ++j) {
      int c = part * 32 + g * 8 + j;
      v[j] = Ls[c][n];
      ph[j] = f2bf(v[j]);
      sum += v[j] * v[j];
    }
    float4 f0 = {v[0], v[1], v[2], v[3]};
    float4 f1 = {v[4], v[5], v[6], v[7]};
    *(float4*)&xt[(size_t)node * CC + part * 32 + g * 8] = f0;
    *(float4*)&xt[(size_t)node * CC + part * 32 + g * 8 + 4] = f1;
    *(ushort8v*)&xhi[(size_t)node * CC + part * 32 + g * 8] = ph;
  }
  sum += __shfl_xor(sum, 1, 64);
  sum += __shfl_xor(sum, 2, 64);
  if (part == 0) hsq[node] = 0.5f * sum;
}

// ---------------------------------------------------------------------------
// Pack W into h2's fragment order: granule g = ((ct*4+ks)*16 + r16)*4 + kg
__global__ void k_wpack(const float* __restrict__ W,
                        unsigned short* __restrict__ Whi,
                        unsigned short* __restrict__ Wlo) {
  int g = blockIdx.x * 256 + threadIdx.x;   // 0..8191 granules
  int kg = g & 3, r16 = (g >> 2) & 15, ks = (g >> 6) & 3, ct = g >> 8;
  int hf = ct * 16 + r16;
  int c0 = ks * 32 + kg * 8;
  ushort8v ph, pl;
#pragma unroll
  for (int j = 0; j < 8; ++j) {
    float v = W[(size_t)(c0 + j) * HF + hf];
    unsigned short hb = f2bf(v);
    ph[j] = hb;
    pl[j] = f2bf(v - bf2f(hb));
  }
  *(ushort8v*)&Whi[(size_t)g * 8] = ph;
  *(ushort8v*)&Wlo[(size_t)g * 8] = pl;
}

// ---------------------------------------------------------------------------
// tau scan, 2 half-subset blocks per query group (512 cands each). Per-lane
// top-EIGHT packed keys (valid-lower-bound: merged 16th of per-lane top-8s
// <= subset 16th -> thr only loosens, survivors only grow). Halved insert
// body (~20 instr) vs top-16. Writes per-(query,half) 16 keys for taumerge.
__launch_bounds__(256)
__global__ void k_tauscan(const unsigned short* __restrict__ xhi,
                          const float* __restrict__ hsq,
                          unsigned int* __restrict__ keys16) {
  __shared__ short8v AS[2][256];           // 8 KB staging (16 nodes x 16 granules)
  __shared__ unsigned int mv[4][16][33];   // 8.4 KB (32 keys/query + pad)
  int bx = blockIdx.x;
  int b = bx & 7, rest = bx >> 3;          // XCD-pinned; rest 0..127
  int qg = rest >> 1, sh = rest & 1;       // scan-half
  int w = threadIdx.x >> 6, lane = threadIdx.x & 63;
  int qcol = lane & 15, kg = lane >> 4;
  int base = b * NN;
  int q = base + qg * 64 + w * 16 + qcol;
  int t0 = sh * 32;

  const short8v* XH = (const short8v*)xhi;   // granules: node*16 + ks*4 + kg
  short8v bh0 = XH[(size_t)q * 16 + kg];
  short8v bh1 = XH[(size_t)q * 16 + 4 + kg];
  short8v bh2 = XH[(size_t)q * 16 + 8 + kg];
  short8v bh3 = XH[(size_t)q * 16 + 12 + kg];

  int snode = w * 4 + (lane >> 4);
  int sgran = (lane & 15) ^ (snode & 15);

  gload16(xhi + ((size_t)(base + t0 * 16 + snode)) * 128 + sgran * 8, &AS[0][w * 64]);
  __syncthreads();

  unsigned int bd[8];
  unsigned int worst = 0;
  int cur = 0;

#pragma unroll 1
  for (int lt = 0; lt < 32; ++lt) {
    if (lt + 1 < 32)
      gload16(xhi + ((size_t)(base + (t0 + lt + 1) * 16 + snode)) * 128 + sgran * 8,
              &AS[cur ^ 1][w * 64]);
    short8v ah0 = AS[cur][qcol * 16 + ((0 + kg) ^ qcol)];
    short8v ah1 = AS[cur][qcol * 16 + ((4 + kg) ^ qcol)];
    short8v ah2 = AS[cur][qcol * 16 + ((8 + kg) ^ qcol)];
    short8v ah3 = AS[cur][qcol * 16 + ((12 + kg) ^ qcol)];
    f32x4 acc = {0.f, 0.f, 0.f, 0.f};
    acc = __builtin_amdgcn_mfma_f32_16x16x32_bf16(ah0, bh0, acc, 0, 0, 0);
    acc = __builtin_amdgcn_mfma_f32_16x16x32_bf16(ah1, bh1, acc, 0, 0, 0);
    acc = __builtin_amdgcn_mfma_f32_16x16x32_bf16(ah2, bh2, acc, 0, 0, 0);
    acc = __builtin_amdgcn_mfma_f32_16x16x32_bf16(ah3, bh3, acc, 0, 0, 0);
    float4 hs = *(const float4*)&hsq[base + (t0 + lt) * 16 + kg * 4];
    float hsa[4] = {hs.x, hs.y, hs.z, hs.w};

    if (lt < 2) {
#pragma unroll
      for (int r = 0; r < 4; ++r) {
        float tv = acc[r] - hsa[r] + 512.0f;
        bd[lt * 4 + r] = (__float_as_uint(tv) & ~1023u) | (1023u - (unsigned)(lt * 4 + r));
      }
      if (lt == 1) {
        unsigned int m0 = umin3(bd[0], bd[1], bd[2]);
        m0 = umin3(m0, bd[3], bd[4]);
        m0 = umin3(m0, bd[5], bd[6]);
        worst = umin2(m0, bd[7]);
      }
    } else {
#pragma unroll
      for (int r = 0; r < 4; ++r) {
        float tv = acc[r] - hsa[r] + 512.0f;
        unsigned int key = (__float_as_uint(tv) & ~1023u) | (1023u - (unsigned)(lt * 4 + r));
        if (key > worst) {
#pragma unroll
          for (int i = 0; i < 8; ++i) bd[i] = (bd[i] == worst) ? key : bd[i];
          unsigned int m0 = umin3(bd[0], bd[1], bd[2]);
          m0 = umin3(m0, bd[3], bd[4]);
          m0 = umin3(m0, bd[5], bd[6]);
          worst = umin2(m0, bd[7]);
        }
      }
    }
    __syncthreads();
    cur ^= 1;
  }

#pragma unroll
  for (int i = 0; i < 8; ++i) mv[w][qcol][kg * 8 + i] = bd[i];
  __syncthreads();

  if (lane < 16) {
    unsigned int tb[16];
#pragma unroll
    for (int i = 0; i < 16; ++i) tb[i] = mv[w][lane][i];
    unsigned int w0 = umin3(tb[0], tb[1], tb[2]);
    w0 = umin3(w0, tb[3], tb[4]);
    w0 = umin3(w0, tb[5], tb[6]);
    w0 = umin2(w0, tb[7]);
    unsigned int w1 = umin3(tb[8], tb[9], tb[10]);
    w1 = umin3(w1, tb[11], tb[12]);
    w1 = umin3(w1, tb[13], tb[14]);
    w1 = umin2(w1, tb[15]);
    unsigned int wst = umin2(w0, w1);
    for (int j = 16; j < 32; ++j) {
      unsigned int v = mv[w][lane][j];
      if (v > wst) {
        bool done = false;
#pragma unroll
        for (int i = 0; i < 16; ++i) {
          bool m = (!done) && (tb[i] == wst);
          done = done || m;
          tb[i] = m ? v : tb[i];
        }
        unsigned int a0 = umin3(tb[0], tb[1], tb[2]);
        a0 = umin3(a0, tb[3], tb[4]);
        a0 = umin3(a0, tb[5], tb[6]);
        a0 = umin2(a0, tb[7]);
        unsigned int a1 = umin3(tb[8], tb[9], tb[10]);
        a1 = umin3(a1, tb[11], tb[12]);
        a1 = umin3(a1, tb[13], tb[14]);
        a1 = umin2(a1, tb[15]);
        wst = umin2(a0, a1);
      }
    }
    int qq = base + qg * 64 + w * 16 + lane;
    unsigned int* o = keys16 + ((size_t)qq * 2 + sh) * 16;
#pragma unroll
    for (int i = 0; i < 16; ++i) o[i] = tb[i];
  }
}

// ---------------------------------------------------------------------------
// Merge per-half top-16 keys -> 16th-largest of union -> thr[q].
__launch_bounds__(256)
__global__ void k_taumerge(const unsigned int* __restrict__ keys16,
                           float* __restrict__ thr) {
  int q = blockIdx.x * 256 + threadIdx.x;
  const unsigned int* kp = keys16 + (size_t)q * 32;
  unsigned int tb[16];
#pragma unroll
  for (int i = 0; i < 16; ++i) tb[i] = kp[i];
  unsigned int w0 = umin3(tb[0], tb[1], tb[2]);
  w0 = umin3(w0, tb[3], tb[4]);
  w0 = umin3(w0, tb[5], tb[6]);
  w0 = umin2(w0, tb[7]);
  unsigned int w1 = umin3(tb[8], tb[9], tb[10]);
  w1 = umin3(w1, tb[11], tb[12]);
  w1 = umin3(w1, tb[13], tb[14]);
  w1 = umin2(w1, tb[15]);
  unsigned int wst = umin2(w0, w1);
#pragma unroll 1
  for (int j = 16; j < 32; ++j) {
    unsigned int v = kp[j];
    if (v > wst) {
      bool done = false;
#pragma unroll
      for (int i = 0; i < 16; ++i) {
        bool m = (!done) && (tb[i] == wst);
        done = done || m;
        tb[i] = m ? v : tb[i];
      }
      unsigned int a0 = umin3(tb[0], tb[1], tb[2]);
      a0 = umin3(a0, tb[3], tb[4]);
      a0 = umin3(a0, tb[5], tb[6]);
      a0 = umin2(a0, tb[7]);
      unsigned int a1 = umin3(tb[8], tb[9], tb[10]);
      a1 = umin3(a1, tb[11], tb[12]);
      a1 = umin3(a1, tb[13], tb[14]);
      a1 = umin2(a1, tb[15]);
      wst = umin2(a0, a1);
    }
  }
  thr[q] = __uint_as_float(wst & ~1023u) - 0.5f;
}

// ---------------------------------------------------------------------------
// Collect survivors (tv >= thr[q]): 2-tile-per-barrier LDS staging + PRIVATE
// per-lane LDS append lists, 4-lane shfl-prefix merge. XCD-pinned.
__launch_bounds__(256)
__global__ void k_collect2(const unsigned short* __restrict__ xhi,
                           const float* __restrict__ hsq,
                           const float* __restrict__ thr,
                           unsigned short* __restrict__ cand,
                           unsigned short* __restrict__ qcnt) {
  __shared__ short8v AS[2][2][256];          // 16 KB staging (2 bufs x 2 tiles)
  __shared__ unsigned short lbuf[256][34];   // 17 KB private lists (pad 34)
  int bx = blockIdx.x;
  int b = bx & 7, rest = bx >> 3;            // XCD-pinned batch; rest 0..127
  int qg = rest >> 1, ht = rest & 1;
  int w = threadIdx.x >> 6, lane = threadIdx.x & 63;
  int tid = threadIdx.x;
  int qcol = lane & 15, kg = lane >> 4;
  int base = b * NN;
  int q = base + qg * 64 + w * 16 + qcol;

  const short8v* XH = (const short8v*)xhi;
  short8v bh0 = XH[(size_t)q * 16 + kg];
  short8v bh1 = XH[(size_t)q * 16 + 4 + kg];
  short8v bh2 = XH[(size_t)q * 16 + 8 + kg];
  short8v bh3 = XH[(size_t)q * 16 + 12 + kg];
  float myThr = thr[q];

  int snode = w * 4 + (lane >> 4);
  int sgran = (lane & 15) ^ (snode & 15);

  int tbase = ht * 128;
  gload16(xhi + ((size_t)(base + (tbase + 0) * 16 + snode)) * 128 + sgran * 8,
          &AS[0][0][w * 64]);
  gload16(xhi + ((size_t)(base + (tbase + 1) * 16 + snode)) * 128 + sgran * 8,
          &AS[0][1][w * 64]);
  __syncthreads();

  int myCnt = 0;
  int cur = 0;

#pragma unroll 1
  for (int lt = 0; lt < 128; lt += 2) {
    if (lt + 2 < 128) {
      gload16(xhi + ((size_t)(base + (tbase + lt + 2) * 16 + snode)) * 128 + sgran * 8,
              &AS[cur ^ 1][0][w * 64]);
      gload16(xhi + ((size_t)(base + (tbase + lt + 3) * 16 + snode)) * 128 + sgran * 8,
              &AS[cur ^ 1][1][w * 64]);
    }
#pragma unroll
    for (int tt = 0; tt < 2; ++tt) {
      int t = tbase + lt + tt;
      short8v ah0 = AS[cur][tt][qcol * 16 + ((0 + kg) ^ qcol)];
      short8v ah1 = AS[cur][tt][qcol * 16 + ((4 + kg) ^ qcol)];
      short8v ah2 = AS[cur][tt][qcol * 16 + ((8 + kg) ^ qcol)];
      short8v ah3 = AS[cur][tt][qcol * 16 + ((12 + kg) ^ qcol)];
      f32x4 acc = {0.f, 0.f, 0.f, 0.f};
      acc = __builtin_amdgcn_mfma_f32_16x16x32_bf16(ah0, bh0, acc, 0, 0, 0);
      acc = __builtin_amdgcn_mfma_f32_16x16x32_bf16(ah1, bh1, acc, 0, 0, 0);
      acc = __builtin_amdgcn_mfma_f32_16x16x32_bf16(ah2, bh2, acc, 0, 0, 0);
      acc = __builtin_amdgcn_mfma_f32_16x16x32_bf16(ah3, bh3, acc, 0, 0, 0);
      float4 hs = *(const float4*)&hsq[base + t * 16 + kg * 4];
      float hsa[4] = {hs.x, hs.y, hs.z, hs.w};
#pragma unroll
      for (int r = 0; r < 4; ++r) {
        float tv = acc[r] - hsa[r] + 512.0f;
        bool pass = (tv >= myThr) && (myCnt < LCAP);
        if (pass) {
          lbuf[tid][myCnt] = (unsigned short)(t * 16 + kg * 4 + r);
          ++myCnt;
        }
      }
    }
    __syncthreads();
    cur ^= 1;
  }

  // merge: prefix over the 4 kg-lanes of this query (lanes qcol+16*kg)
  int c0_ = __shfl(myCnt, qcol, 64);
  int c1_ = __shfl(myCnt, qcol + 16, 64);
  int c2_ = __shfl(myCnt, qcol + 32, 64);
  int c3_ = __shfl(myCnt, qcol + 48, 64);
  int off = (kg > 0 ? c0_ : 0) + (kg > 1 ? c1_ : 0) + (kg > 2 ? c2_ : 0);
  int tot = c0_ + c1_ + c2_ + c3_;        // <= 4*LCAP = CAPH
  unsigned short* dst = cand + (size_t)q * (2 * CAPH) + ht * CAPH + off;
#pragma unroll 1
  for (int i = 0; i < myCnt; ++i) dst[i] = lbuf[tid][i];
  if (kg == 0) qcnt[(size_t)q * 2 + ht] = (unsigned short)tot;
}

// ---------------------------------------------------------------------------
// Exact f32 rerank, 8-lane cooperative dot phase; selection via sortable
// 64-bit keys in LDS + rank-by-broadcast-scan.
__launch_bounds__(256)
__global__ void k_rerank(const float* __restrict__ xt, const float* __restrict__ hsq,
                         const unsigned short* __restrict__ cand,
                         const unsigned short* __restrict__ qcnt,
                         unsigned short* __restrict__ nbr) {
  __shared__ unsigned long long pk[4][256];   // 8 KB sortable keys
  int w = threadIdx.x >> 6;
  int bid = blockIdx.x;
  int b = bid & 7, inner = bid >> 3;      // XCD-pinned batch; inner 0..1023
  int wq = (b << 12) + inner * 4 + w;
  int lane = threadIdx.x & 63;
  int base = b * NN;
  int n0 = qcnt[(size_t)wq * 2];
  int n1 = qcnt[(size_t)wq * 2 + 1];
  int nt = n0 + n1;                       // <= 256, >= 16
  const float* qr = xt + (size_t)wq * CC;
  int cid = lane >> 3, part = lane & 7;

  float4 qv[4];
#pragma unroll
  for (int ph = 0; ph < 4; ++ph)
    qv[ph] = *(const float4*)&qr[ph * 32 + part * 4];

  int npass = (nt + 7) >> 3;
#pragma unroll 2
  for (int p = 0; p < npass; ++p) {
    int j = p * 8 + cid;
    bool valid = j < nt;
    int c = 0;
    if (valid)
      c = (j < n0) ? cand[(size_t)wq * (2 * CAPH) + j]
                   : cand[(size_t)wq * (2 * CAPH) + CAPH + (j - n0)];
    const float* cr = xt + (size_t)(base + c) * CC;
    float acc = 0.f;
#pragma unroll
    for (int ph = 0; ph < 4; ++ph) {
      float4 cv = *(const float4*)&cr[ph * 32 + part * 4];
      acc = fmaf(qv[ph].x, cv.x, acc);
      acc = fmaf(qv[ph].y, cv.y, acc);
      acc = fmaf(qv[ph].z, cv.z, acc);
      acc = fmaf(qv[ph].w, cv.w, acc);
    }
    acc += __shfl_xor(acc, 1, 64);
    acc += __shfl_xor(acc, 2, 64);
    acc += __shfl_xor(acc, 4, 64);
    if (part == 0) {
      float val = acc - hsq[base + c];
      unsigned int sb = __float_as_uint(val);
      sb = (sb & 0x80000000u) ? ~sb : (sb | 0x80000000u);   // sortable bits
      unsigned long long key =
          ((unsigned long long)sb << 16) | (unsigned long long)(65535 - c);
      pk[w][p * 8 + cid] = valid ? key : 0ull;
    }
  }

  unsigned long long sk[4];
#pragma unroll
  for (int s = 0; s < 4; ++s) {
    int j = lane + s * 64;
    sk[s] = (j < nt) ? pk[w][j] : 0ull;
  }

  int rk0 = 0, rk1 = 0, rk2 = 0, rk3 = 0;
  int nslot = (nt + 63) >> 6;             // wave-uniform 1..4
  if (nslot == 1) {
#pragma unroll 4
    for (int j = 0; j < nt; ++j) {
      unsigned long long kj = pk[w][j];
      rk0 += (kj > sk[0]);
    }
  } else if (nslot == 2) {
#pragma unroll 4
    for (int j = 0; j < nt; ++j) {
      unsigned long long kj = pk[w][j];
      rk0 += (kj > sk[0]);
      rk1 += (kj > sk[1]);
    }
  } else {
#pragma unroll 2
    for (int j = 0; j < nt; ++j) {
      unsigned long long kj = pk[w][j];
      rk0 += (kj > sk[0]);
      rk1 += (kj > sk[1]);
      rk2 += (kj > sk[2]);
      rk3 += (kj > sk[3]);
    }
  }

  unsigned short* o = nbr + (size_t)wq * KK;
  {
    int j = lane;
    if (j < nt && rk0 < KK) o[rk0] = (unsigned short)(65535 - (unsigned)(sk[0] & 0xffffull));
    j = lane + 64;
    if (j < nt && rk1 < KK) o[rk1] = (unsigned short)(65535 - (unsigned)(sk[1] & 0xffffull));
    j = lane + 128;
    if (j < nt && rk2 < KK) o[rk2] = (unsigned short)(65535 - (unsigned)(sk[2] & 0xffffull));
    j = lane + 192;
    if (j < nt && rk3 < KK) o[rk3] = (unsigned short)(65535 - (unsigned)(sk[3] & 0xffffull));
  }
}

// ---------------------------------------------------------------------------
// h = xt . W via 3-term split-bf16 MFMA; W fragments in coalesced order.
__launch_bounds__(256)
__global__ void k_h2(const float* __restrict__ xt,
                     const unsigned short* __restrict__ Whi,
                     const unsigned short* __restrict__ Wlo,
                     unsigned short* __restrict__ hout) {
  int w = threadIdx.x >> 6, lane = threadIdx.x & 63;
  int r16 = lane & 15, kg = lane >> 4;
  int nd0 = blockIdx.x * 64 + w * 16;
  const float* arow = xt + (size_t)(nd0 + r16) * CC;
  short8v ahi[4], alo[4];
#pragma unroll
  for (int ks = 0; ks < 4; ++ks) {
    float4 f0 = *(const float4*)&arow[ks * 32 + kg * 8];
    float4 f1 = *(const float4*)&arow[ks * 32 + kg * 8 + 4];
    float fv[8] = {f0.x, f0.y, f0.z, f0.w, f1.x, f1.y, f1.z, f1.w};
    short8v hh_, ll_;
#pragma unroll
    for (int j = 0; j < 8; ++j) {
      unsigned short hb = f2bf(fv[j]);
      hh_[j] = (short)hb;
      ll_[j] = (short)f2bf(fv[j] - bf2f(hb));
    }
    ahi[ks] = hh_; alo[ks] = ll_;
  }
  const short8v* WH = (const short8v*)Whi;
  const short8v* WL = (const short8v*)Wlo;
#pragma unroll 1
  for (int ct = 0; ct < 32; ++ct) {
    int hf = ct * 16 + r16;
    f32x4 acc = {0.f, 0.f, 0.f, 0.f};
#pragma unroll
    for (int ks = 0; ks < 4; ++ks) {
      size_t gidx = (size_t)(((ct * 4 + ks) * 16 + r16) * 4 + kg);
      short8v bh = WH[gidx];
      short8v bl = WL[gidx];
      acc = __builtin_amdgcn_mfma_f32_16x16x32_bf16(ahi[ks], bh, acc, 0, 0, 0);
      acc = __builtin_amdgcn_mfma_f32_16x16x32_bf16(ahi[ks], bl, acc, 0, 0, 0);
      acc = __builtin_amdgcn_mfma_f32_16x16x32_bf16(alo[ks], bh, acc, 0, 0, 0);
    }
#pragma unroll
    for (int r = 0; r < 4; ++r)
      hout[(size_t)(nd0 + kg * 4 + r) * HF + hf] = f2bf(acc[r]);
  }
}

// ---------------------------------------------------------------------------
// a_src/a_dst[b][n][h] = sum_f h[b][n][h][f] * att_{src,dst}[h][f]
__global__ void k_att(const unsigned short* __restrict__ h,
                      const float* __restrict__ att_src, const float* __restrict__ att_dst,
                      float* __restrict__ a_src, float* __restrict__ a_dst) {
  int gid = blockIdx.x * 256 + threadIdx.x;
  int wid = gid >> 6;            // node index b*N+n
  int lane = threadIdx.x & 63;
  uint4 v = ((const uint4*)(h + (size_t)wid * HF))[lane];
  float hv[8];
  hv[0] = bf2f(v.x & 0xffff); hv[1] = bf2f(v.x >> 16);
  hv[2] = bf2f(v.y & 0xffff); hv[3] = bf2f(v.y >> 16);
  hv[4] = bf2f(v.z & 0xffff); hv[5] = bf2f(v.z >> 16);
  hv[6] = bf2f(v.w & 0xffff); hv[7] = bf2f(v.w >> 16);
  int base = lane * 8;
  float s = 0.f, d = 0.f;
#pragma unroll
  for (int i = 0; i < 8; ++i) {
    s += hv[i] * att_src[base + i];
    d += hv[i] * att_dst[base + i];
  }
#pragma unroll
  for (int off = 1; off < 16; off <<= 1) {
    s += __shfl_xor(s, off, 64);
    d += __shfl_xor(d, off, 64);
  }
  if ((lane & 15) == 0) {
    int hh = lane >> 4;
    a_src[wid * HH + hh] = s;
    a_dst[wid * HH + hh] = d;
  }
}

// ---------------------------------------------------------------------------
// gather + softmax(k=16) + weighted sum + head-mean + bias + transpose store
// XCD-pinned: batch = blockIdx & 7.
__launch_bounds__(256)
__global__ void k_out(const unsigned short* __restrict__ h,
                      const unsigned short* __restrict__ nbr,
                      const float* __restrict__ a_src, const float* __restrict__ a_dst,
                      const float* __restrict__ bias, float* __restrict__ out) {
  __shared__ float Ot[FF][17];
  int b = blockIdx.x & 7, nb = blockIdx.x >> 3;   // XCD-pinned batch; nb 0..255
  int w = threadIdx.x >> 6, lane = threadIdx.x & 63;
  int hh = lane >> 4, jj = lane & 15;

  for (int t = 0; t < 4; ++t) {
    int nl = w * 4 + t;
    int node = b * NN + nb * 16 + nl;
    int mj = nbr[node * KK + jj];

    float e = a_src[((size_t)b * NN + mj) * HH + hh] + a_dst[(size_t)node * HH + hh];
    e = e >= 0.f ? e : 0.2f * e;
    float m = e;
#pragma unroll
    for (int off = 1; off < 16; off <<= 1) m = fmaxf(m, __shfl_xor(m, off, 64));
    float p = expf(e - m);
    float sum = p;
#pragma unroll
    for (int off = 1; off < 16; off <<= 1) sum += __shfl_xor(sum, off, 64);
    float alpha = p / sum;

    float acc[8];
#pragma unroll
    for (int i = 0; i < 8; ++i) acc[i] = 0.f;

#pragma unroll
    for (int j = 0; j < 16; ++j) {
      float aj = __shfl(alpha, (hh << 4) | j, 64);
      int m2 = __shfl(mj, j, 64);
      uint4 v = ((const uint4*)(h + (size_t)(b * NN + m2) * HF))[lane];
      acc[0] += aj * bf2f(v.x & 0xffff); acc[1] += aj * bf2f(v.x >> 16);
      acc[2] += aj * bf2f(v.y & 0xffff); acc[3] += aj * bf2f(v.y >> 16);
      acc[4] += aj * bf2f(v.z & 0xffff); acc[5] += aj * bf2f(v.z >> 16);
      acc[6] += aj * bf2f(v.w & 0xffff); acc[7] += aj * bf2f(v.w >> 16);
    }

#pragma unroll
    for (int i = 0; i < 8; ++i) {
      acc[i] += __shfl_xor(acc[i], 16, 64);
      acc[i] += __shfl_xor(acc[i], 32, 64);
    }
    if (hh == 0) {
#pragma unroll
      for (int i = 0; i < 8; ++i) Ot[jj * 8 + i][nl] = acc[i] * 0.25f;
    }
  }
  __syncthreads();

#pragma unroll
  for (int it = 0; it < 8; ++it) {
    int idx = it * 256 + threadIdx.x;
    int f = idx >> 4, nl = idx & 15;
    out[((size_t)b * FF + f) * NN + nb * 16 + nl] = Ot[f][nl] + bias[f];
  }
}

// ---------------------------------------------------------------------------
extern "C" void kernel_launch(void* const* d_in, const int* in_sizes, int n_in,
                              void* d_out, int out_size, void* d_ws, size_t ws_size,
                              hipStream_t stream) {
  const float* x       = (const float*)d_in[0];
  const float* W       = (const float*)d_in[1];
  const float* att_src = (const float*)d_in[2];
  const float* att_dst = (const float*)d_in[3];
  const float* bias    = (const float*)d_in[4];

  char* ws = (char*)d_ws;
  // Lifetime-aliased layout (identical to R15/R16, all sizes verified):
  //   [0        ,16777216): xt    f32 32768*128*4 = 16,777,216 — split..rerank,h2
  //   [16777216 ,25165824): xhi   bf16 32768*128*2 = 8,388,608 — split..collect2
  //   [25165824 ,30360128): keys16 u32 32768*32*4 = 4,194,304  — tauscan..taumerge
  //   [25165824 ,41943040): cand  u16 32768*256*2 = 16,777,216 — collect2..rerank
  //   [16777216 ,50331648): h     bf16 32768*512*2 = 33,554,432 — k_h2 AFTER rerank
  //   [50331648 ,51380224): nbr   u16 32768*16*2 = 1,048,576   — rerank..out
  //   [51380224 ,51511296): qcnt  u16 32768*2*2 = 131,072      — collect2..rerank
  //   [51511296 ,51642368): thr   f32 32768*4 = 131,072        — taumerge..collect2
  //   [51642368 ,51773440): hsq   f32 32768*4 = 131,072        — split..rerank
  //   [51773440 ,52297728): a_src f32 524,288 (aliased early by Whi+Wlo 2*131,072)
  //   [52297728 ,52822016): a_dst f32 524,288
  // total 52,822,016 B (proven envelope)
  float* xt            = (float*)ws;
  unsigned short* xhi  = (unsigned short*)(ws + 16777216);
  unsigned int* keys16 = (unsigned int*)(ws + 25165824);
  unsigned short* cand = (unsigned short*)(ws + 25165824);
  unsigned short* h    = (unsigned short*)(ws + 16777216);
  unsigned short* nbr  = (unsigned short*)(ws + 50331648);
  unsigned short* qcnt = (unsigned short*)(ws + 51380224);
  float* thr   = (float*)(ws + 51511296);
  float* hsq   = (float*)(ws + 51642368);
  float* a_src = (float*)(ws + 51773440);
  unsigned short* Whi  = (unsigned short*)(ws + 51773440);
  unsigned short* Wlo  = (unsigned short*)(ws + 51773440 + 131072);
  float* a_dst = (float*)(ws + 52297728);

  float* out = (float*)d_out;

  k_split   <<<BB * (NN / 64), 256, 0, stream>>>(x, xt, xhi, hsq);
  k_wpack   <<<HF * CC / 8 / 256, 256, 0, stream>>>(W, Whi, Wlo);
  k_tauscan <<<BB * 64 * 2, 256, 0, stream>>>(xhi, hsq, keys16);
  k_taumerge<<<BB * NN / 256, 256, 0, stream>>>(keys16, thr);
  k_collect2<<<BB * 64 * 2, 256, 0, stream>>>(xhi, hsq, thr, cand, qcnt);
  k_rerank  <<<BB * NN / 4, 256, 0, stream>>>(xt, hsq, cand, qcnt, nbr);
  k_h2      <<<BB * NN / 64, 256, 0, stream>>>(xt, Whi, Wlo, h);
  k_att     <<<BB * NN / 4, 256, 0, stream>>>(h, att_src, att_dst, a_src, a_dst);
  k_out     <<<BB * (NN / 16), 256, 0, stream>>>(h, nbr, a_src, a_dst, bias, out);
}

// Round 18
// 289.329 us; speedup vs baseline: 1.3066x; 1.0111x over previous
//
#include <hip/hip_runtime.h>
#include <hip/hip_bf16.h>

#define BB 8
#define CC 128
#define NN 4096
#define HH 4
#define FF 128
#define KK 16
#define HF 512      // H*F
#define CAPH 128    // survivor capacity per query per half (stride 256 total)
#define LCAP2 22    // per-lane per-set private list cap (mu 4.4 + 6.6 sigma)

typedef __attribute__((ext_vector_type(8))) short short8v;
typedef __attribute__((ext_vector_type(8))) unsigned short ushort8v;
typedef __attribute__((ext_vector_type(4))) float f32x4;

__device__ __forceinline__ float bf2f(unsigned int u) {
  return __uint_as_float(u << 16);
}

__device__ __forceinline__ unsigned short f2bf(float f) {
  unsigned int u = __float_as_uint(f);
  unsigned int lsb = (u >> 16) & 1u;
  u += 0x7fffu + lsb;                 // RTNE
  return (unsigned short)(u >> 16);
}

__device__ __forceinline__ unsigned int umin2(unsigned int a, unsigned int b) {
  return a < b ? a : b;
}
__device__ __forceinline__ unsigned int umin3(unsigned int a, unsigned int b, unsigned int c) {
  return umin2(umin2(a, b), c);
}

// async global->LDS, 16B per lane; lds base must be wave-uniform
__device__ __forceinline__ void gload16(const void* gsrc, void* ldst) {
  __builtin_amdgcn_global_load_lds(
      (const __attribute__((address_space(1))) unsigned int*)gsrc,
      (__attribute__((address_space(3))) unsigned int*)ldst, 16, 0, 0);
}

// ---------------------------------------------------------------------------
// x[b][c][n] -> xt[b][n][c] (f32), xhi[b][n][c] (bf16), hsq[b][n] = 0.5*|x|^2
__launch_bounds__(256)
__global__ void k_split(const float* __restrict__ x,
                        float* __restrict__ xt,
                        unsigned short* __restrict__ xhi,
                        float* __restrict__ hsq) {
  __shared__ float Ls[CC][65];
  int b = blockIdx.x >> 6, nb = blockIdx.x & 63;
  int n0 = nb * 64;
  int tid = threadIdx.x;
  const float* xb = x + (size_t)b * CC * NN;

  for (int i = tid; i < CC * 64; i += 256) {
    int c = i >> 6, nl = i & 63;
    Ls[c][nl] = xb[(size_t)c * NN + n0 + nl];
  }
  __syncthreads();

  int n = tid >> 2, part = tid & 3;     // 64 n x 4 parts (32 c each)
  int node = b * NN + n0 + n;
  float sum = 0.f;
#pragma unroll
  for (int g = 0; g < 4; ++g) {
    float v[8];
    ushort8v ph;
#pragma unroll
    for (int j = 0; j < 8; ++j) {
      int c = part * 32 + g * 8 + j;
      v[j] = Ls[c][n];
      ph[j] = f2bf(v[j]);
      sum += v[j] * v[j];
    }
    float4 f0 = {v[0], v[1], v[2], v[3]};
    float4 f1 = {v[4], v[5], v[6], v[7]};
    *(float4*)&xt[(size_t)node * CC + part * 32 + g * 8] = f0;
    *(float4*)&xt[(size_t)node * CC + part * 32 + g * 8 + 4] = f1;
    *(ushort8v*)&xhi[(size_t)node * CC + part * 32 + g * 8] = ph;
  }
  sum += __shfl_xor(sum, 1, 64);
  sum += __shfl_xor(sum, 2, 64);
  if (part == 0) hsq[node] = 0.5f * sum;
}

// ---------------------------------------------------------------------------
// Pack W into h2's fragment order: granule g = ((ct*4+ks)*16 + r16)*4 + kg
__global__ void k_wpack(const float* __restrict__ W,
                        unsigned short* __restrict__ Whi,
                        unsigned short* __restrict__ Wlo) {
  int g = blockIdx.x * 256 + threadIdx.x;   // 0..8191 granules
  int kg = g & 3, r16 = (g >> 2) & 15, ks = (g >> 6) & 3, ct = g >> 8;
  int hf = ct * 16 + r16;
  int c0 = ks * 32 + kg * 8;
  ushort8v ph, pl;
#pragma unroll
  for (int j = 0; j < 8; ++j) {
    float v = W[(size_t)(c0 + j) * HF + hf];
    unsigned short hb = f2bf(v);
    ph[j] = hb;
    pl[j] = f2bf(v - bf2f(hb));
  }
  *(ushort8v*)&Whi[(size_t)g * 8] = ph;
  *(ushort8v*)&Wlo[(size_t)g * 8] = pl;
}

// ---------------------------------------------------------------------------
// tau scan, 2 half-subset blocks per query group (512 cands each). Per-lane
// top-EIGHT packed keys (valid lower bound for thr). XCD-pinned.
__launch_bounds__(256)
__global__ void k_tauscan(const unsigned short* __restrict__ xhi,
                          const float* __restrict__ hsq,
                          unsigned int* __restrict__ keys16) {
  __shared__ short8v AS[2][256];           // 8 KB staging (16 nodes x 16 granules)
  __shared__ unsigned int mv[4][16][33];   // 8.4 KB (32 keys/query + pad)
  int bx = blockIdx.x;
  int b = bx & 7, rest = bx >> 3;          // XCD-pinned; rest 0..127
  int qg = rest >> 1, sh = rest & 1;       // scan-half
  int w = threadIdx.x >> 6, lane = threadIdx.x & 63;
  int qcol = lane & 15, kg = lane >> 4;
  int base = b * NN;
  int q = base + qg * 64 + w * 16 + qcol;
  int t0 = sh * 32;

  const short8v* XH = (const short8v*)xhi;   // granules: node*16 + ks*4 + kg
  short8v bh0 = XH[(size_t)q * 16 + kg];
  short8v bh1 = XH[(size_t)q * 16 + 4 + kg];
  short8v bh2 = XH[(size_t)q * 16 + 8 + kg];
  short8v bh3 = XH[(size_t)q * 16 + 12 + kg];

  int snode = w * 4 + (lane >> 4);
  int sgran = (lane & 15) ^ (snode & 15);

  gload16(xhi + ((size_t)(base + t0 * 16 + snode)) * 128 + sgran * 8, &AS[0][w * 64]);
  __syncthreads();

  unsigned int bd[8];
  unsigned int worst = 0;
  int cur = 0;

#pragma unroll 1
  for (int lt = 0; lt < 32; ++lt) {
    if (lt + 1 < 32)
      gload16(xhi + ((size_t)(base + (t0 + lt + 1) * 16 + snode)) * 128 + sgran * 8,
              &AS[cur ^ 1][w * 64]);
    short8v ah0 = AS[cur][qcol * 16 + ((0 + kg) ^ qcol)];
    short8v ah1 = AS[cur][qcol * 16 + ((4 + kg) ^ qcol)];
    short8v ah2 = AS[cur][qcol * 16 + ((8 + kg) ^ qcol)];
    short8v ah3 = AS[cur][qcol * 16 + ((12 + kg) ^ qcol)];
    f32x4 acc = {0.f, 0.f, 0.f, 0.f};
    acc = __builtin_amdgcn_mfma_f32_16x16x32_bf16(ah0, bh0, acc, 0, 0, 0);
    acc = __builtin_amdgcn_mfma_f32_16x16x32_bf16(ah1, bh1, acc, 0, 0, 0);
    acc = __builtin_amdgcn_mfma_f32_16x16x32_bf16(ah2, bh2, acc, 0, 0, 0);
    acc = __builtin_amdgcn_mfma_f32_16x16x32_bf16(ah3, bh3, acc, 0, 0, 0);
    float4 hs = *(const float4*)&hsq[base + (t0 + lt) * 16 + kg * 4];
    float hsa[4] = {hs.x, hs.y, hs.z, hs.w};

    if (lt < 2) {
#pragma unroll
      for (int r = 0; r < 4; ++r) {
        float tv = acc[r] - hsa[r] + 512.0f;
        bd[lt * 4 + r] = (__float_as_uint(tv) & ~1023u) | (1023u - (unsigned)(lt * 4 + r));
      }
      if (lt == 1) {
        unsigned int m0 = umin3(bd[0], bd[1], bd[2]);
        m0 = umin3(m0, bd[3], bd[4]);
        m0 = umin3(m0, bd[5], bd[6]);
        worst = umin2(m0, bd[7]);
      }
    } else {
#pragma unroll
      for (int r = 0; r < 4; ++r) {
        float tv = acc[r] - hsa[r] + 512.0f;
        unsigned int key = (__float_as_uint(tv) & ~1023u) | (1023u - (unsigned)(lt * 4 + r));
        if (key > worst) {
#pragma unroll
          for (int i = 0; i < 8; ++i) bd[i] = (bd[i] == worst) ? key : bd[i];
          unsigned int m0 = umin3(bd[0], bd[1], bd[2]);
          m0 = umin3(m0, bd[3], bd[4]);
          m0 = umin3(m0, bd[5], bd[6]);
          worst = umin2(m0, bd[7]);
        }
      }
    }
    __syncthreads();
    cur ^= 1;
  }

#pragma unroll
  for (int i = 0; i < 8; ++i) mv[w][qcol][kg * 8 + i] = bd[i];
  __syncthreads();

  if (lane < 16) {
    unsigned int tb[16];
#pragma unroll
    for (int i = 0; i < 16; ++i) tb[i] = mv[w][lane][i];
    unsigned int w0 = umin3(tb[0], tb[1], tb[2]);
    w0 = umin3(w0, tb[3], tb[4]);
    w0 = umin3(w0, tb[5], tb[6]);
    w0 = umin2(w0, tb[7]);
    unsigned int w1 = umin3(tb[8], tb[9], tb[10]);
    w1 = umin3(w1, tb[11], tb[12]);
    w1 = umin3(w1, tb[13], tb[14]);
    w1 = umin2(w1, tb[15]);
    unsigned int wst = umin2(w0, w1);
    for (int j = 16; j < 32; ++j) {
      unsigned int v = mv[w][lane][j];
      if (v > wst) {
        bool done = false;
#pragma unroll
        for (int i = 0; i < 16; ++i) {
          bool m = (!done) && (tb[i] == wst);
          done = done || m;
          tb[i] = m ? v : tb[i];
        }
        unsigned int a0 = umin3(tb[0], tb[1], tb[2]);
        a0 = umin3(a0, tb[3], tb[4]);
        a0 = umin3(a0, tb[5], tb[6]);
        a0 = umin2(a0, tb[7]);
        unsigned int a1 = umin3(tb[8], tb[9], tb[10]);
        a1 = umin3(a1, tb[11], tb[12]);
        a1 = umin3(a1, tb[13], tb[14]);
        a1 = umin2(a1, tb[15]);
        wst = umin2(a0, a1);
      }
    }
    int qq = base + qg * 64 + w * 16 + lane;
    unsigned int* o = keys16 + ((size_t)qq * 2 + sh) * 16;
#pragma unroll
    for (int i = 0; i < 16; ++i) o[i] = tb[i];
  }
}

// ---------------------------------------------------------------------------
// Merge per-half top-16 keys -> 16th-largest of union -> thr[q].
__launch_bounds__(256)
__global__ void k_taumerge(const unsigned int* __restrict__ keys16,
                           float* __restrict__ thr) {
  int q = blockIdx.x * 256 + threadIdx.x;
  const unsigned int* kp = keys16 + (size_t)q * 32;
  unsigned int tb[16];
#pragma unroll
  for (int i = 0; i < 16; ++i) tb[i] = kp[i];
  unsigned int w0 = umin3(tb[0], tb[1], tb[2]);
  w0 = umin3(w0, tb[3], tb[4]);
  w0 = umin3(w0, tb[5], tb[6]);
  w0 = umin2(w0, tb[7]);
  unsigned int w1 = umin3(tb[8], tb[9], tb[10]);
  w1 = umin3(w1, tb[11], tb[12]);
  w1 = umin3(w1, tb[13], tb[14]);
  w1 = umin2(w1, tb[15]);
  unsigned int wst = umin2(w0, w1);
#pragma unroll 1
  for (int j = 16; j < 32; ++j) {
    unsigned int v = kp[j];
    if (v > wst) {
      bool done = false;
#pragma unroll
      for (int i = 0; i < 16; ++i) {
        bool m = (!done) && (tb[i] == wst);
        done = done || m;
        tb[i] = m ? v : tb[i];
      }
      unsigned int a0 = umin3(tb[0], tb[1], tb[2]);
      a0 = umin3(a0, tb[3], tb[4]);
      a0 = umin3(a0, tb[5], tb[6]);
      a0 = umin2(a0, tb[7]);
      unsigned int a1 = umin3(tb[8], tb[9], tb[10]);
      a1 = umin3(a1, tb[11], tb[12]);
      a1 = umin3(a1, tb[13], tb[14]);
      a1 = umin2(a1, tb[15]);
      wst = umin2(a0, a1);
    }
  }
  thr[q] = __uint_as_float(wst & ~1023u) - 0.5f;
}

// ---------------------------------------------------------------------------
// Collect survivors (tv >= thr[q]): each wave holds TWO 16-query B-sets
// (32 queries) and processes tiles of one PARITY -> each staged tile is read
// by 2 waves instead of 4 (ds_read traffic halved). Private per-lane per-set
// lists, cross-wave LDS-count merge. XCD-pinned: batch = blockIdx & 7.
__launch_bounds__(256)
__global__ void k_collect2(const unsigned short* __restrict__ xhi,
                           const float* __restrict__ hsq,
                           const float* __restrict__ thr,
                           unsigned short* __restrict__ cand,
                           unsigned short* __restrict__ qcnt) {
  __shared__ short8v AS[2][2][256];              // [parity][buf] 16 KB
  __shared__ unsigned short lbuf[256][2][22];    // 22.5 KB private lists
  __shared__ unsigned short cnts[256][2];        // 1 KB
  int bx = blockIdx.x;
  int b = bx & 7, rest = bx >> 3;                // XCD-pinned batch
  int qg = rest >> 1, ht = rest & 1;
  int w = threadIdx.x >> 6, lane = threadIdx.x & 63;
  int tid = threadIdx.x;
  int u = w & 1, p = w >> 1;                     // query 32-set, tile parity
  int qcol = lane & 15, kg = lane >> 4;
  int base = b * NN;
  int q0 = base + qg * 64 + u * 32 + qcol;       // set 0 query
  int q1 = q0 + 16;                              // set 1 query

  const short8v* XH = (const short8v*)xhi;
  short8v bh0 = XH[(size_t)q0 * 16 + kg];
  short8v bh1 = XH[(size_t)q0 * 16 + 4 + kg];
  short8v bh2 = XH[(size_t)q0 * 16 + 8 + kg];
  short8v bh3 = XH[(size_t)q0 * 16 + 12 + kg];
  short8v ch0 = XH[(size_t)q1 * 16 + kg];
  short8v ch1 = XH[(size_t)q1 * 16 + 4 + kg];
  short8v ch2 = XH[(size_t)q1 * 16 + 8 + kg];
  short8v ch3 = XH[(size_t)q1 * 16 + 12 + kg];
  float thr0 = thr[q0], thr1 = thr[q1];

  // staging: waves (u=0,p),(u=1,p) cooperatively fill AS[p][buf]:
  // wave u covers linear slots u*128 + i*64 + lane (i=0,1)
  int s0 = u * 128 + lane;                       // i=0 slot
  int s1 = u * 128 + 64 + lane;                  // i=1 slot
  int nd0_ = s0 >> 4, gr0_ = (s0 & 15) ^ (nd0_ & 15);
  int nd1_ = s1 >> 4, gr1_ = (s1 & 15) ^ (nd1_ & 15);

  int tbase = ht * 128;
  {
    int t = tbase + p;
    gload16(xhi + ((size_t)(base + t * 16 + nd0_)) * 128 + gr0_ * 8,
            &AS[p][0][u * 128]);
    gload16(xhi + ((size_t)(base + t * 16 + nd1_)) * 128 + gr1_ * 8,
            &AS[p][0][u * 128 + 64]);
  }
  __syncthreads();

  int cnt0 = 0, cnt1 = 0;
  int cur = 0;

#pragma unroll 1
  for (int it = 0; it < 64; ++it) {
    int t = tbase + it * 2 + p;
    if (it + 1 < 64) {
      int tn = t + 2;
      gload16(xhi + ((size_t)(base + tn * 16 + nd0_)) * 128 + gr0_ * 8,
              &AS[p][cur ^ 1][u * 128]);
      gload16(xhi + ((size_t)(base + tn * 16 + nd1_)) * 128 + gr1_ * 8,
              &AS[p][cur ^ 1][u * 128 + 64]);
    }
    short8v ah0 = AS[p][cur][qcol * 16 + ((0 + kg) ^ qcol)];
    short8v ah1 = AS[p][cur][qcol * 16 + ((4 + kg) ^ qcol)];
    short8v ah2 = AS[p][cur][qcol * 16 + ((8 + kg) ^ qcol)];
    short8v ah3 = AS[p][cur][qcol * 16 + ((12 + kg) ^ qcol)];
    f32x4 a0 = {0.f, 0.f, 0.f, 0.f};
    a0 = __builtin_amdgcn_mfma_f32_16x16x32_bf16(ah0, bh0, a0, 0, 0, 0);
    a0 = __builtin_amdgcn_mfma_f32_16x16x32_bf16(ah1, bh1, a0, 0, 0, 0);
    a0 = __builtin_amdgcn_mfma_f32_16x16x32_bf16(ah2, bh2, a0, 0, 0, 0);
    a0 = __builtin_amdgcn_mfma_f32_16x16x32_bf16(ah3, bh3, a0, 0, 0, 0);
    f32x4 a1 = {0.f, 0.f, 0.f, 0.f};
    a1 = __builtin_amdgcn_mfma_f32_16x16x32_bf16(ah0, ch0, a1, 0, 0, 0);
    a1 = __builtin_amdgcn_mfma_f32_16x16x32_bf16(ah1, ch1, a1, 0, 0, 0);
    a1 = __builtin_amdgcn_mfma_f32_16x16x32_bf16(ah2, ch2, a1, 0, 0, 0);
    a1 = __builtin_amdgcn_mfma_f32_16x16x32_bf16(ah3, ch3, a1, 0, 0, 0);
    float4 hs = *(const float4*)&hsq[base + t * 16 + kg * 4];
    float hsa[4] = {hs.x, hs.y, hs.z, hs.w};
#pragma unroll
    for (int r = 0; r < 4; ++r) {
      unsigned short ci = (unsigned short)(t * 16 + kg * 4 + r);
      float tv0 = a0[r] - hsa[r] + 512.0f;
      if (tv0 >= thr0 && cnt0 < LCAP2) {
        lbuf[tid][0][cnt0] = ci;
        ++cnt0;
      }
      float tv1 = a1[r] - hsa[r] + 512.0f;
      if (tv1 >= thr1 && cnt1 < LCAP2) {
        lbuf[tid][1][cnt1] = ci;
        ++cnt1;
      }
    }
    __syncthreads();
    cur ^= 1;
  }

  cnts[tid][0] = (unsigned short)cnt0;
  cnts[tid][1] = (unsigned short)cnt1;
  __syncthreads();

  // merge: query (u, s, qcol) has 8 contributors (p' in 0..1, kg' in 0..3),
  // order o = p'*4 + kg'. my o = p*4 + kg.
  int myo = p * 4 + kg;
#pragma unroll
  for (int s = 0; s < 2; ++s) {
    int q = base + qg * 64 + u * 32 + s * 16 + qcol;
    int off = 0, tot = 0;
#pragma unroll
    for (int o2 = 0; o2 < 8; ++o2) {
      int p2 = o2 >> 2, kg2 = o2 & 3;
      int ctid = (p2 * 2 + u) * 64 + kg2 * 16 + qcol;
      int c = (int)cnts[ctid][s];
      if (o2 < myo) off += c;
      tot += c;
    }
    int myCnt = (s == 0) ? cnt0 : cnt1;
    unsigned short* dst = cand + (size_t)q * (2 * CAPH) + ht * CAPH;
#pragma unroll 1
    for (int i = 0; i < myCnt; ++i) {
      int pos = off + i;
      if (pos < CAPH) dst[pos] = lbuf[tid][s][i];
    }
    if (myo == 0) {
      if (tot > CAPH) tot = CAPH;
      qcnt[(size_t)q * 2 + ht] = (unsigned short)tot;
    }
  }
}

// ---------------------------------------------------------------------------
// Exact f32 rerank, 8-lane cooperative dot phase; selection via sortable
// 64-bit keys in LDS + rank-by-broadcast-scan.
__launch_bounds__(256)
__global__ void k_rerank(const float* __restrict__ xt, const float* __restrict__ hsq,
                         const unsigned short* __restrict__ cand,
                         const unsigned short* __restrict__ qcnt,
                         unsigned short* __restrict__ nbr) {
  __shared__ unsigned long long pk[4][256];   // 8 KB sortable keys
  int w = threadIdx.x >> 6;
  int bid = blockIdx.x;
  int b = bid & 7, inner = bid >> 3;      // XCD-pinned batch; inner 0..1023
  int wq = (b << 12) + inner * 4 + w;
  int lane = threadIdx.x & 63;
  int base = b * NN;
  int n0 = qcnt[(size_t)wq * 2];
  int n1 = qcnt[(size_t)wq * 2 + 1];
  int nt = n0 + n1;                       // <= 256, >= 16
  const float* qr = xt + (size_t)wq * CC;
  int cid = lane >> 3, part = lane & 7;

  float4 qv[4];
#pragma unroll
  for (int ph = 0; ph < 4; ++ph)
    qv[ph] = *(const float4*)&qr[ph * 32 + part * 4];

  int npass = (nt + 7) >> 3;
#pragma unroll 2
  for (int p = 0; p < npass; ++p) {
    int j = p * 8 + cid;
    bool valid = j < nt;
    int c = 0;
    if (valid)
      c = (j < n0) ? cand[(size_t)wq * (2 * CAPH) + j]
                   : cand[(size_t)wq * (2 * CAPH) + CAPH + (j - n0)];
    const float* cr = xt + (size_t)(base + c) * CC;
    float acc = 0.f;
#pragma unroll
    for (int ph = 0; ph < 4; ++ph) {
      float4 cv = *(const float4*)&cr[ph * 32 + part * 4];
      acc = fmaf(qv[ph].x, cv.x, acc);
      acc = fmaf(qv[ph].y, cv.y, acc);
      acc = fmaf(qv[ph].z, cv.z, acc);
      acc = fmaf(qv[ph].w, cv.w, acc);
    }
    acc += __shfl_xor(acc, 1, 64);
    acc += __shfl_xor(acc, 2, 64);
    acc += __shfl_xor(acc, 4, 64);
    if (part == 0) {
      float val = acc - hsq[base + c];
      unsigned int sb = __float_as_uint(val);
      sb = (sb & 0x80000000u) ? ~sb : (sb | 0x80000000u);   // sortable bits
      unsigned long long key =
          ((unsigned long long)sb << 16) | (unsigned long long)(65535 - c);
      pk[w][p * 8 + cid] = valid ? key : 0ull;
    }
  }

  unsigned long long sk[4];
#pragma unroll
  for (int s = 0; s < 4; ++s) {
    int j = lane + s * 64;
    sk[s] = (j < nt) ? pk[w][j] : 0ull;
  }

  int rk0 = 0, rk1 = 0, rk2 = 0, rk3 = 0;
  int nslot = (nt + 63) >> 6;             // wave-uniform 1..4
  if (nslot == 1) {
#pragma unroll 4
    for (int j = 0; j < nt; ++j) {
      unsigned long long kj = pk[w][j];
      rk0 += (kj > sk[0]);
    }
  } else if (nslot == 2) {
#pragma unroll 4
    for (int j = 0; j < nt; ++j) {
      unsigned long long kj = pk[w][j];
      rk0 += (kj > sk[0]);
      rk1 += (kj > sk[1]);
    }
  } else {
#pragma unroll 2
    for (int j = 0; j < nt; ++j) {
      unsigned long long kj = pk[w][j];
      rk0 += (kj > sk[0]);
      rk1 += (kj > sk[1]);
      rk2 += (kj > sk[2]);
      rk3 += (kj > sk[3]);
    }
  }

  unsigned short* o = nbr + (size_t)wq * KK;
  {
    int j = lane;
    if (j < nt && rk0 < KK) o[rk0] = (unsigned short)(65535 - (unsigned)(sk[0] & 0xffffull));
    j = lane + 64;
    if (j < nt && rk1 < KK) o[rk1] = (unsigned short)(65535 - (unsigned)(sk[1] & 0xffffull));
    j = lane + 128;
    if (j < nt && rk2 < KK) o[rk2] = (unsigned short)(65535 - (unsigned)(sk[2] & 0xffffull));
    j = lane + 192;
    if (j < nt && rk3 < KK) o[rk3] = (unsigned short)(65535 - (unsigned)(sk[3] & 0xffffull));
  }
}

// ---------------------------------------------------------------------------
// h = xt . W via 3-term split-bf16 MFMA; W fragments in coalesced order.
__launch_bounds__(256)
__global__ void k_h2(const float* __restrict__ xt,
                     const unsigned short* __restrict__ Whi,
                     const unsigned short* __restrict__ Wlo,
                     unsigned short* __restrict__ hout) {
  int w = threadIdx.x >> 6, lane = threadIdx.x & 63;
  int r16 = lane & 15, kg = lane >> 4;
  int nd0 = blockIdx.x * 64 + w * 16;
  const float* arow = xt + (size_t)(nd0 + r16) * CC;
  short8v ahi[4], alo[4];
#pragma unroll
  for (int ks = 0; ks < 4; ++ks) {
    float4 f0 = *(const float4*)&arow[ks * 32 + kg * 8];
    float4 f1 = *(const float4*)&arow[ks * 32 + kg * 8 + 4];
    float fv[8] = {f0.x, f0.y, f0.z, f0.w, f1.x, f1.y, f1.z, f1.w};
    short8v hh_, ll_;
#pragma unroll
    for (int j = 0; j < 8; ++j) {
      unsigned short hb = f2bf(fv[j]);
      hh_[j] = (short)hb;
      ll_[j] = (short)f2bf(fv[j] - bf2f(hb));
    }
    ahi[ks] = hh_; alo[ks] = ll_;
  }
  const short8v* WH = (const short8v*)Whi;
  const short8v* WL = (const short8v*)Wlo;
#pragma unroll 1
  for (int ct = 0; ct < 32; ++ct) {
    int hf = ct * 16 + r16;
    f32x4 acc = {0.f, 0.f, 0.f, 0.f};
#pragma unroll
    for (int ks = 0; ks < 4; ++ks) {
      size_t gidx = (size_t)(((ct * 4 + ks) * 16 + r16) * 4 + kg);
      short8v bh = WH[gidx];
      short8v bl = WL[gidx];
      acc = __builtin_amdgcn_mfma_f32_16x16x32_bf16(ahi[ks], bh, acc, 0, 0, 0);
      acc = __builtin_amdgcn_mfma_f32_16x16x32_bf16(ahi[ks], bl, acc, 0, 0, 0);
      acc = __builtin_amdgcn_mfma_f32_16x16x32_bf16(alo[ks], bh, acc, 0, 0, 0);
    }
#pragma unroll
    for (int r = 0; r < 4; ++r)
      hout[(size_t)(nd0 + kg * 4 + r) * HF + hf] = f2bf(acc[r]);
  }
}

// ---------------------------------------------------------------------------
// a_src/a_dst[b][n][h] = sum_f h[b][n][h][f] * att_{src,dst}[h][f]
__global__ void k_att(const unsigned short* __restrict__ h,
                      const float* __restrict__ att_src, const float* __restrict__ att_dst,
                      float* __restrict__ a_src, float* __restrict__ a_dst) {
  int gid = blockIdx.x * 256 + threadIdx.x;
  int wid = gid >> 6;            // node index b*N+n
  int lane = threadIdx.x & 63;
  uint4 v = ((const uint4*)(h + (size_t)wid * HF))[lane];
  float hv[8];
  hv[0] = bf2f(v.x & 0xffff); hv[1] = bf2f(v.x >> 16);
  hv[2] = bf2f(v.y & 0xffff); hv[3] = bf2f(v.y >> 16);
  hv[4] = bf2f(v.z & 0xffff); hv[5] = bf2f(v.z >> 16);
  hv[6] = bf2f(v.w & 0xffff); hv[7] = bf2f(v.w >> 16);
  int base = lane * 8;
  float s = 0.f, d = 0.f;
#pragma unroll
  for (int i = 0; i < 8; ++i) {
    s += hv[i] * att_src[base + i];
    d += hv[i] * att_dst[base + i];
  }
#pragma unroll
  for (int off = 1; off < 16; off <<= 1) {
    s += __shfl_xor(s, off, 64);
    d += __shfl_xor(d, off, 64);
  }
  if ((lane & 15) == 0) {
    int hh = lane >> 4;
    a_src[wid * HH + hh] = s;
    a_dst[wid * HH + hh] = d;
  }
}

// ---------------------------------------------------------------------------
// gather + softmax(k=16) + weighted sum + head-mean + bias + transpose store
// XCD-pinned: batch = blockIdx & 7.
__launch_bounds__(256)
__global__ void k_out(const unsigned short* __restrict__ h,
                      const unsigned short* __restrict__ nbr,
                      const float* __restrict__ a_src, const float* __restrict__ a_dst,
                      const float* __restrict__ bias, float* __restrict__ out) {
  __shared__ float Ot[FF][17];
  int b = blockIdx.x & 7, nb = blockIdx.x >> 3;   // XCD-pinned batch; nb 0..255
  int w = threadIdx.x >> 6, lane = threadIdx.x & 63;
  int hh = lane >> 4, jj = lane & 15;

  for (int t = 0; t < 4; ++t) {
    int nl = w * 4 + t;
    int node = b * NN + nb * 16 + nl;
    int mj = nbr[node * KK + jj];

    float e = a_src[((size_t)b * NN + mj) * HH + hh] + a_dst[(size_t)node * HH + hh];
    e = e >= 0.f ? e : 0.2f * e;
    float m = e;
#pragma unroll
    for (int off = 1; off < 16; off <<= 1) m = fmaxf(m, __shfl_xor(m, off, 64));
    float p = expf(e - m);
    float sum = p;
#pragma unroll
    for (int off = 1; off < 16; off <<= 1) sum += __shfl_xor(sum, off, 64);
    float alpha = p / sum;

    float acc[8];
#pragma unroll
    for (int i = 0; i < 8; ++i) acc[i] = 0.f;

#pragma unroll
    for (int j = 0; j < 16; ++j) {
      float aj = __shfl(alpha, (hh << 4) | j, 64);
      int m2 = __shfl(mj, j, 64);
      uint4 v = ((const uint4*)(h + (size_t)(b * NN + m2) * HF))[lane];
      acc[0] += aj * bf2f(v.x & 0xffff); acc[1] += aj * bf2f(v.x >> 16);
      acc[2] += aj * bf2f(v.y & 0xffff); acc[3] += aj * bf2f(v.y >> 16);
      acc[4] += aj * bf2f(v.z & 0xffff); acc[5] += aj * bf2f(v.z >> 16);
      acc[6] += aj * bf2f(v.w & 0xffff); acc[7] += aj * bf2f(v.w >> 16);
    }

#pragma unroll
    for (int i = 0; i < 8; ++i) {
      acc[i] += __shfl_xor(acc[i], 16, 64);
      acc[i] += __shfl_xor(acc[i], 32, 64);
    }
    if (hh == 0) {
#pragma unroll
      for (int i = 0; i < 8; ++i) Ot[jj * 8 + i][nl] = acc[i] * 0.25f;
    }
  }
  __syncthreads();

#pragma unroll
  for (int it = 0; it < 8; ++it) {
    int idx = it * 256 + threadIdx.x;
    int f = idx >> 4, nl = idx & 15;
    out[((size_t)b * FF + f) * NN + nb * 16 + nl] = Ot[f][nl] + bias[f];
  }
}

// ---------------------------------------------------------------------------
extern "C" void kernel_launch(void* const* d_in, const int* in_sizes, int n_in,
                              void* d_out, int out_size, void* d_ws, size_t ws_size,
                              hipStream_t stream) {
  const float* x       = (const float*)d_in[0];
  const float* W       = (const float*)d_in[1];
  const float* att_src = (const float*)d_in[2];
  const float* att_dst = (const float*)d_in[3];
  const float* bias    = (const float*)d_in[4];

  char* ws = (char*)d_ws;
  // Lifetime-aliased layout (identical to R15-R17, all sizes verified):
  //   [0        ,16777216): xt    f32 32768*128*4 = 16,777,216 — split..rerank,h2
  //   [16777216 ,25165824): xhi   bf16 32768*128*2 = 8,388,608 — split..collect2
  //   [25165824 ,30360128): keys16 u32 32768*32*4 = 4,194,304  — tauscan..taumerge
  //   [25165824 ,41943040): cand  u16 32768*256*2 = 16,777,216 — collect2..rerank
  //   [16777216 ,50331648): h     bf16 32768*512*2 = 33,554,432 — k_h2 AFTER rerank
  //   [50331648 ,51380224): nbr   u16 32768*16*2 = 1,048,576   — rerank..out
  //   [51380224 ,51511296): qcnt  u16 32768*2*2 = 131,072      — collect2..rerank
  //   [51511296 ,51642368): thr   f32 32768*4 = 131,072        — taumerge..collect2
  //   [51642368 ,51773440): hsq   f32 32768*4 = 131,072        — split..rerank
  //   [51773440 ,52297728): a_src f32 524,288 (aliased early by Whi+Wlo 2*131,072)
  //   [52297728 ,52822016): a_dst f32 524,288
  // total 52,822,016 B (proven envelope)
  float* xt            = (float*)ws;
  unsigned short* xhi  = (unsigned short*)(ws + 16777216);
  unsigned int* keys16 = (unsigned int*)(ws + 25165824);
  unsigned short* cand = (unsigned short*)(ws + 25165824);
  unsigned short* h    = (unsigned short*)(ws + 16777216);
  unsigned short* nbr  = (unsigned short*)(ws + 50331648);
  unsigned short* qcnt = (unsigned short*)(ws + 51380224);
  float* thr   = (float*)(ws + 51511296);
  float* hsq   = (float*)(ws + 51642368);
  float* a_src = (float*)(ws + 51773440);
  unsigned short* Whi  = (unsigned short*)(ws + 51773440);
  unsigned short* Wlo  = (unsigned short*)(ws + 51773440 + 131072);
  float* a_dst = (float*)(ws + 52297728);

  float* out = (float*)d_out;

  k_split   <<<BB * (NN / 64), 256, 0, stream>>>(x, xt, xhi, hsq);
  k_wpack   <<<HF * CC / 8 / 256, 256, 0, stream>>>(W, Whi, Wlo);
  k_tauscan <<<BB * 64 * 2, 256, 0, stream>>>(xhi, hsq, keys16);
  k_taumerge<<<BB * NN / 256, 256, 0, stream>>>(keys16, thr);
  k_collect2<<<BB * 64 * 2, 256, 0, stream>>>(xhi, hsq, thr, cand, qcnt);
  k_rerank  <<<BB * NN / 4, 256, 0, stream>>>(xt, hsq, cand, qcnt, nbr);
  k_h2      <<<BB * NN / 64, 256, 0, stream>>>(xt, Whi, Wlo, h);
  k_att     <<<BB * NN / 4, 256, 0, stream>>>(h, att_src, att_dst, a_src, a_dst);
  k_out     <<<BB * (NN / 16), 256, 0, stream>>>(h, nbr, a_src, a_dst, bias, out);
}